// Round 4
// baseline (1471.284 us; speedup 1.0000x reference)
//
#include <hip/hip_runtime.h>
#include <cstdint>
#include <cstddef>

// ---------------------------------------------------------------------------
// MoE: router (fp32 + f64 ambiguity redo) -> top-2 lists -> expert MLP (fp16
// MFMA) -> gated scatter.
// B=16384, D=1024, E=8, C=50, RH=512/256, H1=2048, H2=1024, top_k=2
//
// Workspace budget (ws_size unknown; R2 core-dump suspect = overflow):
// liveness unions cut 305MB -> ~238MB:
//   arenaA (67.4MB): [x16 | Wt1] (die after expert L1)  ∪  h2 (born L2)
//   arenaB (134.7MB): [h1r | h2r] (die after router)    ∪  h1 (born L1)
//   Wt2 33.5MB, Wt3 1MB, ctrl+lists ~1.2MB
// ---------------------------------------------------------------------------

typedef __attribute__((ext_vector_type(4))) float    f32x4;
typedef __attribute__((ext_vector_type(8))) _Float16 f16x8;
typedef __attribute__((ext_vector_type(4))) _Float16 f16x4;

#define DEVI __device__ __forceinline__

constexpr int NTOK = 16384;
constexpr int DIM  = 1024;
constexpr int NEXP = 8;
constexpr int COUT = 50;
constexpr int RH1  = 512;
constexpr int RH2  = 256;
constexpr int H1   = 2048;
constexpr int H2   = 1024;
constexpr int CAP  = NTOK;          // per-expert token capacity (worst case)
constexpr int TOTROWS = 2 * NTOK;   // exact total selected rows (top_k = 2)

// global -> LDS direct copy, 16B per lane
DEVI void gload_lds16(const void* g, void* l) {
  auto gg = (const __attribute__((address_space(1))) uint32_t*)(uintptr_t)g;
  auto ll = (__attribute__((address_space(3))) uint32_t*)(uintptr_t)l;
  __builtin_amdgcn_global_load_lds(gg, ll, 16, 0, 0);
}

// ---------------------------------------------------------------------------
// zero-init kernels (graph-capture-safe; harness poisons ws/out with 0xAA)
// ---------------------------------------------------------------------------
__global__ void zero_ctrl(int* c) { if (threadIdx.x < 32) c[threadIdx.x] = 0; }

__global__ __launch_bounds__(256) void zero_out(float* __restrict__ o) {
  const int i = (blockIdx.x * 256 + threadIdx.x) * 4;
  if (i < NTOK * COUT) *(f32x4*)&o[i] = (f32x4)0.0f;
}

// ---------------------------------------------------------------------------
// fp32 -> fp16 elementwise convert (4 elems / thread)
// ---------------------------------------------------------------------------
__global__ __launch_bounds__(256) void cvt_f32_f16(const float* __restrict__ in,
                                                   _Float16* __restrict__ out, int n) {
  int i = (blockIdx.x * 256 + threadIdx.x) * 4;
  if (i < n) {
    f32x4 v = *(const f32x4*)&in[i];
    f16x4 h;
    h[0] = (_Float16)v[0]; h[1] = (_Float16)v[1];
    h[2] = (_Float16)v[2]; h[3] = (_Float16)v[3];
    *(f16x4*)&out[i] = h;
  }
}

// ---------------------------------------------------------------------------
// transpose + convert: in [E][R][Cc] f32 -> out [E][Cpad][R] f16 (pad rows = 0)
// grid: (Cpad/32, R/32, E), block 256 (32x8)
// ---------------------------------------------------------------------------
__global__ __launch_bounds__(256) void cvtT(const float* __restrict__ in,
                                            _Float16* __restrict__ out,
                                            int R, int Cc, int Cpad) {
  __shared__ float tile[32][33];
  const int e = blockIdx.z;
  const float*  ip = in  + (size_t)e * R * Cc;
  _Float16*     op = out + (size_t)e * Cpad * R;
  const int tx = threadIdx.x & 31, ty = threadIdx.x >> 5;
  const int c = blockIdx.x * 32 + tx;
#pragma unroll
  for (int j = 0; j < 4; ++j) {
    const int r = blockIdx.y * 32 + ty + j * 8;
    tile[ty + j * 8][tx] = (c < Cc) ? ip[(size_t)r * Cc + c] : 0.0f;
  }
  __syncthreads();
  const int ocol = blockIdx.y * 32 + tx;   // = input row
#pragma unroll
  for (int j = 0; j < 4; ++j) {
    const int orow = blockIdx.x * 32 + ty + j * 8;  // = input col (padded)
    op[(size_t)orow * R + ocol] = (_Float16)tile[tx][ty + j * 8];
  }
}

// ---------------------------------------------------------------------------
// fp32 GEMM (router): C = relu(A[M,K] @ Bw[K,N] + bias), tile 128x64, BK=16
// ---------------------------------------------------------------------------
template <bool RELU>
__global__ __launch_bounds__(256) void sgemm_rt(const float* __restrict__ A,
                                                const float* __restrict__ Bw,
                                                const float* __restrict__ bias,
                                                float* __restrict__ C,
                                                int M, int K, int N) {
  __shared__ float As[16 * 128];  // [k][m]
  __shared__ float Bs[16 * 64];   // [k][n]
  const int tid = threadIdx.x;
  const int row0 = blockIdx.y * 128, col0 = blockIdx.x * 64;
  const int tr = tid >> 4, tc = tid & 15;
  float acc[8][4];
#pragma unroll
  for (int i = 0; i < 8; ++i)
#pragma unroll
    for (int j = 0; j < 4; ++j) acc[i][j] = 0.0f;

  const int arow = tid >> 1, ak = (tid & 1) * 8;
  const int bk = tid >> 4, bc = (tid & 15) * 4;

  for (int k0 = 0; k0 < K; k0 += 16) {
    const f32x4 a0 = *(const f32x4*)&A[(size_t)(row0 + arow) * K + k0 + ak];
    const f32x4 a1 = *(const f32x4*)&A[(size_t)(row0 + arow) * K + k0 + ak + 4];
    const f32x4 b0 = *(const f32x4*)&Bw[(size_t)(k0 + bk) * N + col0 + bc];
    __syncthreads();
#pragma unroll
    for (int j = 0; j < 4; ++j) {
      As[(ak + j) * 128 + arow]     = a0[j];
      As[(ak + 4 + j) * 128 + arow] = a1[j];
    }
    *(f32x4*)&Bs[bk * 64 + bc] = b0;
    __syncthreads();
#pragma unroll
    for (int k = 0; k < 16; ++k) {
      const f32x4 av0 = *(const f32x4*)&As[k * 128 + tr * 8];
      const f32x4 av1 = *(const f32x4*)&As[k * 128 + tr * 8 + 4];
      const f32x4 bv  = *(const f32x4*)&Bs[k * 64 + tc * 4];
#pragma unroll
      for (int i = 0; i < 4; ++i)
#pragma unroll
        for (int j = 0; j < 4; ++j) {
          acc[i][j]     += av0[i] * bv[j];
          acc[i + 4][j] += av1[i] * bv[j];
        }
    }
  }
#pragma unroll
  for (int i = 0; i < 8; ++i) {
    const int row = row0 + tr * 8 + i;
    f32x4 v;
#pragma unroll
    for (int j = 0; j < 4; ++j) {
      float t = acc[i][j] + bias[col0 + tc * 4 + j];
      v[j] = RELU ? fmaxf(t, 0.0f) : t;
    }
    *(f32x4*)&C[(size_t)row * N + col0 + tc * 4] = v;
  }
}

// ---------------------------------------------------------------------------
// router layer 3 + softmax + top-2 select. Ambiguous tokens (rank2/rank3 gap
// below TAU) go to the f64 redo list. block = 256 tokens.
// ---------------------------------------------------------------------------
__global__ __launch_bounds__(256) void router_score(const float* __restrict__ h2r,
                                                    const float* __restrict__ rW3,
                                                    const float* __restrict__ rb3,
                                                    float* __restrict__ probs_out,
                                                    int* __restrict__ sel,
                                                    int* __restrict__ redoList,
                                                    int* __restrict__ redoCnt) {
  __shared__ float w3[256 * 8];
  __shared__ float tile[256 * 20];  // stride 20 floats: 16B-aligned + bank-spread
  const int tid = threadIdx.x;
  const int t0 = blockIdx.x * 256;
  for (int i = tid; i < 256 * 8; i += 256) w3[i] = rW3[i];
  float acc[8];
#pragma unroll
  for (int e = 0; e < 8; ++e) acc[e] = 0.0f;

  for (int kc = 0; kc < RH2; kc += 16) {
    __syncthreads();
#pragma unroll
    for (int i = 0; i < 4; ++i) {
      const int r = (tid >> 2) + i * 64, q = tid & 3;
      const f32x4 v = *(const f32x4*)&h2r[(size_t)(t0 + r) * RH2 + kc + q * 4];
      *(f32x4*)&tile[r * 20 + q * 4] = v;
    }
    __syncthreads();
#pragma unroll
    for (int k = 0; k < 16; ++k) {
      const float hv = tile[tid * 20 + k];
#pragma unroll
      for (int e = 0; e < 8; ++e) acc[e] += hv * w3[(kc + k) * 8 + e];
    }
  }

  float s[8], mx = -1e30f;
#pragma unroll
  for (int e = 0; e < 8; ++e) { s[e] = acc[e] + rb3[e]; mx = fmaxf(mx, s[e]); }
  float p[8], sum = 0.0f;
#pragma unroll
  for (int e = 0; e < 8; ++e) { p[e] = expf(s[e] - mx); sum += p[e]; }
  const float inv = 1.0f / sum;
#pragma unroll
  for (int e = 0; e < 8; ++e) {
    p[e] *= inv;
    probs_out[(size_t)(t0 + tid) * 8 + e] = p[e];
  }
  // top-2 (strict > keeps lowest index on ties, matching jax.lax.top_k)
  int i1 = 0;
#pragma unroll
  for (int e = 1; e < 8; ++e) if (s[e] > s[i1]) i1 = e;
  int i2 = (i1 == 0) ? 1 : 0;
#pragma unroll
  for (int e = 0; e < 8; ++e) if (e != i1 && s[e] > s[i2]) i2 = e;
  // third-best, for the ambiguity gap
  int i3 = -1;
#pragma unroll
  for (int e = 0; e < 8; ++e)
    if (e != i1 && e != i2 && (i3 < 0 || s[e] > s[i3])) i3 = e;

  const int tok = t0 + tid;
  sel[tok] = i1 * 8 + i2;
  if (s[i2] - s[i3] < 3e-4f) {
    const int pos = atomicAdd(redoCnt, 1);
    redoList[pos] = tok;
  }
}

// ---------------------------------------------------------------------------
// exact (f64) router recompute for ambiguous tokens; one block per token.
// ---------------------------------------------------------------------------
__global__ __launch_bounds__(256)
void router_redo(const float* __restrict__ x,
                 const float* __restrict__ rW1, const float* __restrict__ rb1,
                 const float* __restrict__ rW2, const float* __restrict__ rb2,
                 const float* __restrict__ rW3, const float* __restrict__ rb3,
                 const int* __restrict__ redoList, const int* __restrict__ redoCnt,
                 int* __restrict__ sel) {
  __shared__ double sh1[512];
  __shared__ double sh2[256];
  __shared__ double sred[256];
  const int tid = threadIdx.x;
  const int n = *redoCnt;
  for (int it = blockIdx.x; it < n; it += gridDim.x) {
    const int tok = redoList[it];
    const float* xr = x + (size_t)tok * DIM;
#pragma unroll
    for (int c = 0; c < 2; ++c) {
      const int nn = c * 256 + tid;
      double a = (double)rb1[nn];
      for (int k = 0; k < DIM; ++k)
        a += (double)xr[k] * (double)rW1[(size_t)k * RH1 + nn];
      sh1[nn] = a > 0.0 ? a : 0.0;
    }
    __syncthreads();
    {
      double a = (double)rb2[tid];
      for (int k = 0; k < RH1; ++k)
        a += sh1[k] * (double)rW2[(size_t)k * RH2 + tid];
      sh2[tid] = a > 0.0 ? a : 0.0;
    }
    __syncthreads();
    {
      const int e = tid >> 5;
      double a = 0.0;
      for (int k = tid & 31; k < RH2; k += 32)
        a += sh2[k] * (double)rW3[(size_t)k * 8 + e];
      sred[tid] = a;
    }
    __syncthreads();
    if (tid < 8) {   // one wave: loads all issue before the store in-order
      double s = (double)rb3[tid];
      for (int j = 0; j < 32; ++j) s += sred[tid * 32 + j];
      sred[tid] = s;
    }
    __syncthreads();
    if (tid == 0) {
      double s[8];
#pragma unroll
      for (int e = 0; e < 8; ++e) s[e] = sred[e];
      int i1 = 0;
      for (int e = 1; e < 8; ++e) if (s[e] > s[i1]) i1 = e;
      int i2 = (i1 == 0) ? 1 : 0;
      for (int e = 0; e < 8; ++e) if (e != i1 && s[e] > s[i2]) i2 = e;
      sel[tok] = i1 * 8 + i2;
    }
    __syncthreads();
  }
}

// ---------------------------------------------------------------------------
// scatter (token, gate) into per-expert lists. grid 64 x 256.
// ---------------------------------------------------------------------------
__global__ __launch_bounds__(256)
void build_lists(const int* __restrict__ sel, const float* __restrict__ probs,
                 int* __restrict__ counts, int* __restrict__ tokList,
                 float* __restrict__ gateList) {
  const int tok = blockIdx.x * 256 + threadIdx.x;
  const int sl = sel[tok];
  const int e1 = sl >> 3, e2 = sl & 7;
  const float p1 = probs[(size_t)tok * 8 + e1] * 0.5f;   // /top_k
  const float p2 = probs[(size_t)tok * 8 + e2] * 0.5f;
  int pos = atomicAdd(&counts[e1], 1);
  tokList[e1 * CAP + pos] = tok; gateList[e1 * CAP + pos] = p1;
  pos = atomicAdd(&counts[e2], 1);
  tokList[e2 * CAP + pos] = tok; gateList[e2 * CAP + pos] = p2;
}

__global__ void scan_counts(const int* __restrict__ counts, int* __restrict__ offs) {
  if (threadIdx.x == 0 && blockIdx.x == 0) {
    int s = 0;
    for (int e = 0; e < NEXP; ++e) { offs[e] = s; s += counts[e]; }
  }
}

// ---------------------------------------------------------------------------
// fp16 MFMA GEMM (expert layers 1/2): C[rows,N] = act(A @ Wt[e]^T + bias[e])
// tile 128x128, BK=64, 4 waves (2x2), 4x4 frags of 16x16x32 per wave.
// ---------------------------------------------------------------------------
template <int K, int N, bool GATHER, bool RELU>
__global__ __launch_bounds__(256)
void expert_gemm(const _Float16* __restrict__ Asrc,
                 const _Float16* __restrict__ Wt,    // [E][N][K]
                 const float* __restrict__ bias,     // [E][N]
                 _Float16* __restrict__ Cdst,        // [TOTROWS+128][N]
                 const int* __restrict__ counts,
                 const int* __restrict__ offs,
                 const int* __restrict__ tokList) {
  const int e = blockIdx.z;
  const int cnt = counts[e];
  const int row0 = blockIdx.y * 128;
  if (row0 >= cnt) return;
  const int off = offs[e];
  const int col0 = blockIdx.x * 128;

  __shared__ _Float16 As[128 * 64];
  __shared__ _Float16 Bs[128 * 64];

  const int tid = threadIdx.x;
  const int w = tid >> 6, l = tid & 63;
  const int fr = l & 15, fq = l >> 4;
  const int wm = w >> 1, wn = w & 1;

  // slot s = i*256+tid -> row r=s>>3, granule g=s&7; inverse swizzle on source
  const _Float16* aPtr[4];
  const _Float16* bPtr[4];
#pragma unroll
  for (int i = 0; i < 4; ++i) {
    const int s = i * 256 + tid;
    const int r = s >> 3, g = s & 7;
    const int gs = g ^ (r & 7);
    int arow;
    if (GATHER) {
      int pos = row0 + r;
      pos = pos < cnt ? pos : cnt - 1;
      arow = tokList[e * CAP + pos];
    } else {
      arow = off + row0 + r;
    }
    aPtr[i] = Asrc + (size_t)arow * K + gs * 8;
    bPtr[i] = Wt + ((size_t)e * N + col0 + r) * K + gs * 8;
  }

  f32x4 acc[4][4];
#pragma unroll
  for (int m = 0; m < 4; ++m)
#pragma unroll
    for (int n = 0; n < 4; ++n) acc[m][n] = (f32x4)0.0f;

  for (int k0 = 0; k0 < K; k0 += 64) {
#pragma unroll
    for (int i = 0; i < 4; ++i)
      gload_lds16(aPtr[i] + k0, (void*)(As + (size_t)(i * 256 + w * 64) * 8));
#pragma unroll
    for (int i = 0; i < 4; ++i)
      gload_lds16(bPtr[i] + k0, (void*)(Bs + (size_t)(i * 256 + w * 64) * 8));
    __syncthreads();
#pragma unroll
    for (int kk = 0; kk < 2; ++kk) {
      f16x8 av[4], bv[4];
#pragma unroll
      for (int m = 0; m < 4; ++m) {
        const int ra = wm * 64 + m * 16 + fr;
        av[m] = *(const f16x8*)&As[ra * 64 + (((kk * 4 + fq) ^ (fr & 7)) << 3)];
      }
#pragma unroll
      for (int n = 0; n < 4; ++n) {
        const int rb = wn * 64 + n * 16 + fr;
        bv[n] = *(const f16x8*)&Bs[rb * 64 + (((kk * 4 + fq) ^ (fr & 7)) << 3)];
      }
#pragma unroll
      for (int m = 0; m < 4; ++m)
#pragma unroll
        for (int n = 0; n < 4; ++n)
          acc[m][n] = __builtin_amdgcn_mfma_f32_16x16x32_f16(av[m], bv[n], acc[m][n], 0, 0, 0);
    }
    __syncthreads();
  }

  // C/D layout: col = lane&15, row = (lane>>4)*4 + reg  [m89 verified]
#pragma unroll
  for (int n = 0; n < 4; ++n) {
    const int col = col0 + wn * 64 + n * 16 + fr;
    const float bc = bias[e * N + col];
#pragma unroll
    for (int m = 0; m < 4; ++m) {
      const int rp = row0 + wm * 64 + m * 16 + fq * 4;
#pragma unroll
      for (int j = 0; j < 4; ++j) {
        if (rp + j < cnt) {
          float v = acc[m][n][j] + bc;
          if (RELU) v = fmaxf(v, 0.0f);
          Cdst[(size_t)(off + rp + j) * N + col] = (_Float16)v;
        }
      }
    }
  }
}

// ---------------------------------------------------------------------------
// expert layer 3 + gated scatter: oe = h2 @ Wt3[e]^T + eb3; out[tok] += gate*oe
// tile 128x64 (N padded 50->64), 4 waves (2x2), 4x2 frags. K=1024.
// ---------------------------------------------------------------------------
__global__ __launch_bounds__(256)
void expert_out(const _Float16* __restrict__ h2,    // [TOTROWS+128][1024]
                const _Float16* __restrict__ Wt3,   // [E][64][1024]
                const float* __restrict__ eb3,      // [E][50]
                float* __restrict__ outp,           // [NTOK][50]
                const int* __restrict__ counts,
                const int* __restrict__ offs,
                const int* __restrict__ tokList,
                const float* __restrict__ gateList) {
  const int e = blockIdx.z;
  const int cnt = counts[e];
  const int row0 = blockIdx.y * 128;
  if (row0 >= cnt) return;
  const int off = offs[e];

  __shared__ _Float16 As[128 * 64];
  __shared__ _Float16 Bs[64 * 64];

  const int tid = threadIdx.x;
  const int w = tid >> 6, l = tid & 63;
  const int fr = l & 15, fq = l >> 4;
  const int wm = w >> 1, wn = w & 1;

  const _Float16* aPtr[4];
  const _Float16* bPtr[2];
#pragma unroll
  for (int i = 0; i < 4; ++i) {
    const int s = i * 256 + tid;
    const int r = s >> 3, g = s & 7;
    aPtr[i] = h2 + (size_t)(off + row0 + r) * 1024 + (g ^ (r & 7)) * 8;
  }
#pragma unroll
  for (int i = 0; i < 2; ++i) {
    const int s = i * 256 + tid;
    const int r = s >> 3, g = s & 7;
    bPtr[i] = Wt3 + ((size_t)e * 64 + r) * 1024 + (g ^ (r & 7)) * 8;
  }

  f32x4 acc[4][2];
#pragma unroll
  for (int m = 0; m < 4; ++m)
#pragma unroll
    for (int n = 0; n < 2; ++n) acc[m][n] = (f32x4)0.0f;

  for (int k0 = 0; k0 < 1024; k0 += 64) {
#pragma unroll
    for (int i = 0; i < 4; ++i)
      gload_lds16(aPtr[i] + k0, (void*)(As + (size_t)(i * 256 + w * 64) * 8));
#pragma unroll
    for (int i = 0; i < 2; ++i)
      gload_lds16(bPtr[i] + k0, (void*)(Bs + (size_t)(i * 256 + w * 64) * 8));
    __syncthreads();
#pragma unroll
    for (int kk = 0; kk < 2; ++kk) {
      f16x8 av[4], bv[2];
#pragma unroll
      for (int m = 0; m < 4; ++m) {
        const int ra = wm * 64 + m * 16 + fr;
        av[m] = *(const f16x8*)&As[ra * 64 + (((kk * 4 + fq) ^ (fr & 7)) << 3)];
      }
#pragma unroll
      for (int n = 0; n < 2; ++n) {
        const int rb = wn * 32 + n * 16 + fr;
        bv[n] = *(const f16x8*)&Bs[rb * 64 + (((kk * 4 + fq) ^ (fr & 7)) << 3)];
      }
#pragma unroll
      for (int m = 0; m < 4; ++m)
#pragma unroll
        for (int n = 0; n < 2; ++n)
          acc[m][n] = __builtin_amdgcn_mfma_f32_16x16x32_f16(av[m], bv[n], acc[m][n], 0, 0, 0);
    }
    __syncthreads();
  }

#pragma unroll
  for (int m = 0; m < 4; ++m) {
    const int rp = row0 + wm * 64 + m * 16 + fq * 4;
#pragma unroll
    for (int j = 0; j < 4; ++j) {
      const int pos = rp + j;
      if (pos < cnt) {
        const int tok = tokList[e * CAP + pos];
        const float gate = gateList[e * CAP + pos];
#pragma unroll
        for (int n = 0; n < 2; ++n) {
          const int col = wn * 32 + n * 16 + fr;
          if (col < COUT) {
            const float v = acc[m][n][j] + eb3[e * COUT + col];
            atomicAdd(&outp[(size_t)tok * COUT + col], gate * v);
          }
        }
      }
    }
  }
}

// ---------------------------------------------------------------------------
extern "C" void kernel_launch(void* const* d_in, const int* in_sizes, int n_in,
                              void* d_out, int out_size, void* d_ws, size_t ws_size,
                              hipStream_t stream) {
  const float* x   = (const float*)d_in[0];
  const float* rW1 = (const float*)d_in[1];
  const float* rb1 = (const float*)d_in[2];
  const float* rW2 = (const float*)d_in[3];
  const float* rb2 = (const float*)d_in[4];
  const float* rW3 = (const float*)d_in[5];
  const float* rb3 = (const float*)d_in[6];
  const float* eW1 = (const float*)d_in[7];
  const float* eb1 = (const float*)d_in[8];
  const float* eW2 = (const float*)d_in[9];
  const float* eb2 = (const float*)d_in[10];
  const float* eW3 = (const float*)d_in[11];
  const float* eb3 = (const float*)d_in[12];

  float* outp  = (float*)d_out;                       // [16384][50]
  float* probs = outp + (size_t)NTOK * COUT;          // [16384][8]

  // ---- workspace carve with liveness unions (~238 MB total) ----
  constexpr size_t SZ_X16 = (size_t)NTOK * DIM * 2;            // 33.55 MB
  constexpr size_t SZ_WT1 = (size_t)NEXP * H1 * DIM * 2;       // 33.55 MB
  constexpr size_t SZ_H2  = (size_t)(TOTROWS + 128) * H2 * 2;  // 67.37 MB
  constexpr size_t SZ_A   = (SZ_H2 > SZ_X16 + SZ_WT1) ? SZ_H2 : (SZ_X16 + SZ_WT1);
  constexpr size_t SZ_H1R = (size_t)NTOK * RH1 * 4;            // 33.55 MB
  constexpr size_t SZ_H2R = (size_t)NTOK * RH2 * 4;            // 16.78 MB
  constexpr size_t SZ_H1  = (size_t)(TOTROWS + 128) * H1 * 2;  // 134.74 MB
  constexpr size_t SZ_B   = (SZ_H1 > SZ_H1R + SZ_H2R) ? SZ_H1 : (SZ_H1R + SZ_H2R);

  char* p = (char*)d_ws;
  auto carve = [&](size_t bytes) {
    char* r = p;
    p += (bytes + 255) & ~(size_t)255;
    return r;
  };
  char* arenaA = carve(SZ_A);            // [x16 | Wt1]  ∪  h2
  char* arenaB = carve(SZ_B);            // [h1r | h2r]  ∪  h1
  _Float16* Wt2 = (_Float16*)carve((size_t)NEXP * H2 * H1 * 2);  // 33.55 MB
  _Float16* Wt3 = (_Float16*)carve((size_t)NEXP * 64 * H2 * 2);  // 1 MB
  int*   ctrl    = (int*)carve(128);     // counts[0..7], redoCnt[8], offs[16..23]
  int*   counts  = ctrl;
  int*   redoCnt = ctrl + 8;
  int*   offs    = ctrl + 16;
  int*   sel     = (int*)carve((size_t)NTOK * 4);
  int*   redoList= (int*)carve((size_t)NTOK * 4);
  int*   tokList = (int*)carve((size_t)NEXP * CAP * 4);
  float* gateList= (float*)carve((size_t)NEXP * CAP * 4);

  // arena members (time-disjoint):
  _Float16* x16 = (_Float16*)arenaA;                 // live: conv .. expert L1
  _Float16* Wt1 = (_Float16*)(arenaA + SZ_X16);      // live: conv .. expert L1
  _Float16* h2  = (_Float16*)arenaA;                 // live: expert L2 .. L3
  float* h1r = (float*)arenaB;                       // live: router
  float* h2r = (float*)(arenaB + SZ_H1R);            // live: router
  _Float16* h1 = (_Float16*)arenaB;                  // live: expert L1 .. L2

  // ---- zero init (kernels, not memset: graph-capture insurance) ----
  zero_ctrl<<<1, 64, 0, stream>>>(ctrl);
  zero_out<<<800, 256, 0, stream>>>(outp);

  // ---- conversions ----
  cvt_f32_f16<<<(NTOK * DIM) / (256 * 4), 256, 0, stream>>>(x, x16, NTOK * DIM);
  cvtT<<<dim3(H1 / 32, DIM / 32, NEXP), 256, 0, stream>>>(eW1, Wt1, DIM, H1, H1);
  cvtT<<<dim3(H2 / 32, H1 / 32, NEXP), 256, 0, stream>>>(eW2, Wt2, H1, H2, H2);
  cvtT<<<dim3(64 / 32, H2 / 32, NEXP), 256, 0, stream>>>(eW3, Wt3, H2, COUT, 64);

  // ---- router ----
  sgemm_rt<true><<<dim3(RH1 / 64, NTOK / 128), 256, 0, stream>>>(x, rW1, rb1, h1r, NTOK, DIM, RH1);
  sgemm_rt<true><<<dim3(RH2 / 64, NTOK / 128), 256, 0, stream>>>(h1r, rW2, rb2, h2r, NTOK, RH1, RH2);
  router_score<<<NTOK / 256, 256, 0, stream>>>(h2r, rW3, rb3, probs, sel, redoList, redoCnt);
  router_redo<<<64, 256, 0, stream>>>(x, rW1, rb1, rW2, rb2, rW3, rb3, redoList, redoCnt, sel);
  build_lists<<<NTOK / 256, 256, 0, stream>>>(sel, probs, counts, tokList, gateList);
  scan_counts<<<1, 64, 0, stream>>>(counts, offs);

  // ---- experts (fp16 MFMA, top-2 gathered compact rows) ----
  expert_gemm<DIM, H1, true, true>
      <<<dim3(H1 / 128, CAP / 128, NEXP), 256, 0, stream>>>(x16, Wt1, eb1, h1, counts, offs, tokList);
  expert_gemm<H1, H2, false, true>
      <<<dim3(H2 / 128, CAP / 128, NEXP), 256, 0, stream>>>(h1, Wt2, eb2, h2, counts, offs, tokList);
  expert_out<<<dim3(1, CAP / 128, NEXP), 256, 0, stream>>>(h2, Wt3, eb3, outp, counts, offs, tokList, gateList);

  (void)in_sizes; (void)n_in; (void)out_size; (void)ws_size;
}

// Round 5
// 1409.271 us; speedup vs baseline: 1.0440x; 1.0440x over previous
//
#include <hip/hip_runtime.h>
#include <cstdint>
#include <cstddef>

// ---------------------------------------------------------------------------
// MoE: router (fp32 + f64 ambiguity redo) -> top-2 lists -> expert MLP (fp16
// MFMA, 2-phase double-buffered) -> gated scatter.
// B=16384, D=1024, E=8, C=50, RH=512/256, H1=2048, H2=1024, top_k=2
//
// R4 -> R5: (1) T3 minimum-2-phase dbuf LDS in expert kernels (stage next
// K-tile before computing current; single barrier per step). (2) flattened
// padded row-block grids (no empty blocks; grid.y=264). (3) reg-prefetch in
// router sgemm. Workspace ~245 MB (R4's 238 MB layout proven).
// ---------------------------------------------------------------------------

typedef __attribute__((ext_vector_type(4))) float    f32x4;
typedef __attribute__((ext_vector_type(8))) _Float16 f16x8;
typedef __attribute__((ext_vector_type(4))) _Float16 f16x4;

#define DEVI __device__ __forceinline__

constexpr int NTOK = 16384;
constexpr int DIM  = 1024;
constexpr int NEXP = 8;
constexpr int COUT = 50;
constexpr int RH1  = 512;
constexpr int RH2  = 256;
constexpr int H1   = 2048;
constexpr int H2   = 1024;
constexpr int CAP  = NTOK;           // per-expert token capacity (worst case)
constexpr int TOTROWS = 2 * NTOK;    // exact total selected rows (top_k = 2)
constexpr int PADROWS = TOTROWS + NEXP * 128 + 128;  // padded compact rows
constexpr int MAXRB   = 264;         // max padded row-blocks (256 + 8)

// ctrl layout (ints): [0..7] counts, [8] redoCnt, [9..17] rbStart, [18..25] offsP
// global -> LDS direct copy, 16B per lane
DEVI void gload_lds16(const void* g, void* l) {
  auto gg = (const __attribute__((address_space(1))) uint32_t*)(uintptr_t)g;
  auto ll = (__attribute__((address_space(3))) uint32_t*)(uintptr_t)l;
  __builtin_amdgcn_global_load_lds(gg, ll, 16, 0, 0);
}

// ---------------------------------------------------------------------------
__global__ void zero_ctrl(int* c) { if (threadIdx.x < 32) c[threadIdx.x] = 0; }

__global__ __launch_bounds__(256) void zero_out(float* __restrict__ o) {
  const int i = (blockIdx.x * 256 + threadIdx.x) * 4;
  if (i < NTOK * COUT) *(f32x4*)&o[i] = (f32x4)0.0f;
}

// ---------------------------------------------------------------------------
__global__ __launch_bounds__(256) void cvt_f32_f16(const float* __restrict__ in,
                                                   _Float16* __restrict__ out, int n) {
  int i = (blockIdx.x * 256 + threadIdx.x) * 4;
  if (i < n) {
    f32x4 v = *(const f32x4*)&in[i];
    f16x4 h;
    h[0] = (_Float16)v[0]; h[1] = (_Float16)v[1];
    h[2] = (_Float16)v[2]; h[3] = (_Float16)v[3];
    *(f16x4*)&out[i] = h;
  }
}

// transpose + convert: in [E][R][Cc] f32 -> out [E][Cpad][R] f16 (pad rows = 0)
__global__ __launch_bounds__(256) void cvtT(const float* __restrict__ in,
                                            _Float16* __restrict__ out,
                                            int R, int Cc, int Cpad) {
  __shared__ float tile[32][33];
  const int e = blockIdx.z;
  const float*  ip = in  + (size_t)e * R * Cc;
  _Float16*     op = out + (size_t)e * Cpad * R;
  const int tx = threadIdx.x & 31, ty = threadIdx.x >> 5;
  const int c = blockIdx.x * 32 + tx;
#pragma unroll
  for (int j = 0; j < 4; ++j) {
    const int r = blockIdx.y * 32 + ty + j * 8;
    tile[ty + j * 8][tx] = (c < Cc) ? ip[(size_t)r * Cc + c] : 0.0f;
  }
  __syncthreads();
  const int ocol = blockIdx.y * 32 + tx;
#pragma unroll
  for (int j = 0; j < 4; ++j) {
    const int orow = blockIdx.x * 32 + ty + j * 8;
    op[(size_t)orow * R + ocol] = (_Float16)tile[tx][ty + j * 8];
  }
}

// ---------------------------------------------------------------------------
// fp32 GEMM (router): C = relu(A[M,K] @ Bw[K,N] + bias), tile 128x64, BK=16,
// register prefetch of next K-tile over the compute phase.
// ---------------------------------------------------------------------------
template <bool RELU>
__global__ __launch_bounds__(256) void sgemm_rt(const float* __restrict__ A,
                                                const float* __restrict__ Bw,
                                                const float* __restrict__ bias,
                                                float* __restrict__ C,
                                                int M, int K, int N) {
  __shared__ float As[16 * 128];  // [k][m]
  __shared__ float Bs[16 * 64];   // [k][n]
  const int tid = threadIdx.x;
  const int row0 = blockIdx.y * 128, col0 = blockIdx.x * 64;
  const int tr = tid >> 4, tc = tid & 15;
  float acc[8][4];
#pragma unroll
  for (int i = 0; i < 8; ++i)
#pragma unroll
    for (int j = 0; j < 4; ++j) acc[i][j] = 0.0f;

  const int arow = tid >> 1, ak = (tid & 1) * 8;
  const int bk = tid >> 4, bc = (tid & 15) * 4;

  f32x4 a0 = *(const f32x4*)&A[(size_t)(row0 + arow) * K + ak];
  f32x4 a1 = *(const f32x4*)&A[(size_t)(row0 + arow) * K + ak + 4];
  f32x4 b0 = *(const f32x4*)&Bw[(size_t)bk * N + col0 + bc];

  for (int k0 = 0; k0 < K; k0 += 16) {
    __syncthreads();
#pragma unroll
    for (int j = 0; j < 4; ++j) {
      As[(ak + j) * 128 + arow]     = a0[j];
      As[(ak + 4 + j) * 128 + arow] = a1[j];
    }
    *(f32x4*)&Bs[bk * 64 + bc] = b0;
    __syncthreads();
    if (k0 + 16 < K) {   // prefetch next tile into regs over the compute phase
      a0 = *(const f32x4*)&A[(size_t)(row0 + arow) * K + k0 + 16 + ak];
      a1 = *(const f32x4*)&A[(size_t)(row0 + arow) * K + k0 + 16 + ak + 4];
      b0 = *(const f32x4*)&Bw[(size_t)(k0 + 16 + bk) * N + col0 + bc];
    }
#pragma unroll
    for (int k = 0; k < 16; ++k) {
      const f32x4 av0 = *(const f32x4*)&As[k * 128 + tr * 8];
      const f32x4 av1 = *(const f32x4*)&As[k * 128 + tr * 8 + 4];
      const f32x4 bv  = *(const f32x4*)&Bs[k * 64 + tc * 4];
#pragma unroll
      for (int i = 0; i < 4; ++i)
#pragma unroll
        for (int j = 0; j < 4; ++j) {
          acc[i][j]     += av0[i] * bv[j];
          acc[i + 4][j] += av1[i] * bv[j];
        }
    }
  }
#pragma unroll
  for (int i = 0; i < 8; ++i) {
    const int row = row0 + tr * 8 + i;
    f32x4 v;
#pragma unroll
    for (int j = 0; j < 4; ++j) {
      float t = acc[i][j] + bias[col0 + tc * 4 + j];
      v[j] = RELU ? fmaxf(t, 0.0f) : t;
    }
    *(f32x4*)&C[(size_t)row * N + col0 + tc * 4] = v;
  }
}

// ---------------------------------------------------------------------------
// router layer 3 + softmax + top-2 select; ambiguous tokens -> f64 redo list.
// ---------------------------------------------------------------------------
__global__ __launch_bounds__(256) void router_score(const float* __restrict__ h2r,
                                                    const float* __restrict__ rW3,
                                                    const float* __restrict__ rb3,
                                                    float* __restrict__ probs_out,
                                                    int* __restrict__ sel,
                                                    int* __restrict__ redoList,
                                                    int* __restrict__ redoCnt) {
  __shared__ float w3[256 * 8];
  __shared__ float tile[256 * 20];
  const int tid = threadIdx.x;
  const int t0 = blockIdx.x * 256;
  for (int i = tid; i < 256 * 8; i += 256) w3[i] = rW3[i];
  float acc[8];
#pragma unroll
  for (int e = 0; e < 8; ++e) acc[e] = 0.0f;

  for (int kc = 0; kc < RH2; kc += 16) {
    __syncthreads();
#pragma unroll
    for (int i = 0; i < 4; ++i) {
      const int r = (tid >> 2) + i * 64, q = tid & 3;
      const f32x4 v = *(const f32x4*)&h2r[(size_t)(t0 + r) * RH2 + kc + q * 4];
      *(f32x4*)&tile[r * 20 + q * 4] = v;
    }
    __syncthreads();
#pragma unroll
    for (int k = 0; k < 16; ++k) {
      const float hv = tile[tid * 20 + k];
#pragma unroll
      for (int e = 0; e < 8; ++e) acc[e] += hv * w3[(kc + k) * 8 + e];
    }
  }

  float s[8], mx = -1e30f;
#pragma unroll
  for (int e = 0; e < 8; ++e) { s[e] = acc[e] + rb3[e]; mx = fmaxf(mx, s[e]); }
  float p[8], sum = 0.0f;
#pragma unroll
  for (int e = 0; e < 8; ++e) { p[e] = expf(s[e] - mx); sum += p[e]; }
  const float inv = 1.0f / sum;
#pragma unroll
  for (int e = 0; e < 8; ++e) {
    p[e] *= inv;
    probs_out[(size_t)(t0 + tid) * 8 + e] = p[e];
  }
  int i1 = 0;
#pragma unroll
  for (int e = 1; e < 8; ++e) if (s[e] > s[i1]) i1 = e;
  int i2 = (i1 == 0) ? 1 : 0;
#pragma unroll
  for (int e = 0; e < 8; ++e) if (e != i1 && s[e] > s[i2]) i2 = e;
  int i3 = -1;
#pragma unroll
  for (int e = 0; e < 8; ++e)
    if (e != i1 && e != i2 && (i3 < 0 || s[e] > s[i3])) i3 = e;

  const int tok = t0 + tid;
  sel[tok] = i1 * 8 + i2;
  if (s[i2] - s[i3] < 3e-4f) {
    const int pos = atomicAdd(redoCnt, 1);
    redoList[pos] = tok;
  }
}

// ---------------------------------------------------------------------------
// exact (f64) router recompute for ambiguous tokens; one block per token.
// ---------------------------------------------------------------------------
__global__ __launch_bounds__(256)
void router_redo(const float* __restrict__ x,
                 const float* __restrict__ rW1, const float* __restrict__ rb1,
                 const float* __restrict__ rW2, const float* __restrict__ rb2,
                 const float* __restrict__ rW3, const float* __restrict__ rb3,
                 const int* __restrict__ redoList, const int* __restrict__ redoCnt,
                 int* __restrict__ sel) {
  __shared__ double sh1[512];
  __shared__ double sh2[256];
  __shared__ double sred[256];
  const int tid = threadIdx.x;
  const int n = *redoCnt;
  for (int it = blockIdx.x; it < n; it += gridDim.x) {
    const int tok = redoList[it];
    const float* xr = x + (size_t)tok * DIM;
#pragma unroll
    for (int c = 0; c < 2; ++c) {
      const int nn = c * 256 + tid;
      double a = (double)rb1[nn];
      for (int k = 0; k < DIM; ++k)
        a += (double)xr[k] * (double)rW1[(size_t)k * RH1 + nn];
      sh1[nn] = a > 0.0 ? a : 0.0;
    }
    __syncthreads();
    {
      double a = (double)rb2[tid];
      for (int k = 0; k < RH1; ++k)
        a += sh1[k] * (double)rW2[(size_t)k * RH2 + tid];
      sh2[tid] = a > 0.0 ? a : 0.0;
    }
    __syncthreads();
    {
      const int e = tid >> 5;
      double a = 0.0;
      for (int k = tid & 31; k < RH2; k += 32)
        a += sh2[k] * (double)rW3[(size_t)k * 8 + e];
      sred[tid] = a;
    }
    __syncthreads();
    if (tid < 8) {
      double s = (double)rb3[tid];
      for (int j = 0; j < 32; ++j) s += sred[tid * 32 + j];
      sred[tid] = s;
    }
    __syncthreads();
    if (tid == 0) {
      double s[8];
#pragma unroll
      for (int e = 0; e < 8; ++e) s[e] = sred[e];
      int i1 = 0;
      for (int e = 1; e < 8; ++e) if (s[e] > s[i1]) i1 = e;
      int i2 = (i1 == 0) ? 1 : 0;
      for (int e = 0; e < 8; ++e) if (e != i1 && s[e] > s[i2]) i2 = e;
      sel[tok] = i1 * 8 + i2;
    }
    __syncthreads();
  }
}

// ---------------------------------------------------------------------------
__global__ __launch_bounds__(256)
void build_lists(const int* __restrict__ sel, const float* __restrict__ probs,
                 int* __restrict__ counts, int* __restrict__ tokList,
                 float* __restrict__ gateList) {
  const int tok = blockIdx.x * 256 + threadIdx.x;
  const int sl = sel[tok];
  const int e1 = sl >> 3, e2 = sl & 7;
  const float p1 = probs[(size_t)tok * 8 + e1] * 0.5f;
  const float p2 = probs[(size_t)tok * 8 + e2] * 0.5f;
  int pos = atomicAdd(&counts[e1], 1);
  tokList[e1 * CAP + pos] = tok; gateList[e1 * CAP + pos] = p1;
  pos = atomicAdd(&counts[e2], 1);
  tokList[e2 * CAP + pos] = tok; gateList[e2 * CAP + pos] = p2;
}

// padded scan: rbStart[e] (row-blocks), offsP[e] (padded element offsets)
__global__ void scan_counts(int* __restrict__ ctrl) {
  if (threadIdx.x == 0 && blockIdx.x == 0) {
    int rb = 0, s = 0;
    for (int e = 0; e < NEXP; ++e) {
      ctrl[9 + e]  = rb;
      ctrl[18 + e] = s;
      const int nrb = (ctrl[e] + 127) >> 7;
      rb += nrb; s += nrb * 128;
    }
    ctrl[17] = rb;   // total active row-blocks
  }
}

// ---------------------------------------------------------------------------
// fp16 MFMA GEMM (expert layers 1/2), 2-phase dbuf: tile 128x128, BK=64,
// 4 waves, 4x4 frags of 16x16x32. Flattened padded row-block grid (y=MAXRB).
// ---------------------------------------------------------------------------
template <int K, int N, bool GATHER, bool RELU>
__global__ __launch_bounds__(256)
void expert_gemm(const _Float16* __restrict__ Asrc,
                 const _Float16* __restrict__ Wt,    // [E][N][K]
                 const float* __restrict__ bias,     // [E][N]
                 _Float16* __restrict__ Cdst,        // [PADROWS][N]
                 const int* __restrict__ ctrl,
                 const int* __restrict__ tokList) {
  const int rb = blockIdx.y;
  if (rb >= ctrl[17]) return;
  int e = 0;
#pragma unroll
  for (int q = 1; q < 8; ++q) if (rb >= ctrl[9 + q]) e = q;
  const int cnt  = ctrl[e];
  const int off  = ctrl[18 + e];
  const int row0 = (rb - ctrl[9 + e]) * 128;
  const int col0 = blockIdx.x * 128;

  __shared__ _Float16 As[2][128 * 64];
  __shared__ _Float16 Bs[2][128 * 64];

  const int tid = threadIdx.x;
  const int w = tid >> 6, l = tid & 63;
  const int fr = l & 15, fq = l >> 4;
  const int wm = w >> 1, wn = w & 1;

  // slot s = i*256+tid -> row r=s>>3, granule g=s&7; inverse swizzle on source
  const _Float16* aPtr[4];
  const _Float16* bPtr[4];
#pragma unroll
  for (int i = 0; i < 4; ++i) {
    const int s = i * 256 + tid;
    const int r = s >> 3, g = s & 7;
    const int gs = g ^ (r & 7);
    int arow;
    if (GATHER) {
      int pos = row0 + r;
      pos = pos < cnt ? pos : cnt - 1;
      arow = tokList[e * CAP + pos];
    } else {
      arow = off + row0 + r;
    }
    aPtr[i] = Asrc + (size_t)arow * K + gs * 8;
    bPtr[i] = Wt + ((size_t)e * N + col0 + r) * K + gs * 8;
  }

  auto STAGE = [&](int b, int k0) {
#pragma unroll
    for (int i = 0; i < 4; ++i)
      gload_lds16(aPtr[i] + k0, (void*)&As[b][(i * 256 + w * 64) * 8]);
#pragma unroll
    for (int i = 0; i < 4; ++i)
      gload_lds16(bPtr[i] + k0, (void*)&Bs[b][(i * 256 + w * 64) * 8]);
  };

  f32x4 acc[4][4];
#pragma unroll
  for (int m = 0; m < 4; ++m)
#pragma unroll
    for (int n = 0; n < 4; ++n) acc[m][n] = (f32x4)0.0f;

  constexpr int NT = K / 64;
  STAGE(0, 0);
  __syncthreads();           // compiler drains vmcnt before s_barrier
  int cur = 0;
  for (int t = 0; t < NT; ++t) {
    if (t + 1 < NT) STAGE(cur ^ 1, (t + 1) * 64);   // overlap with compute
#pragma unroll
    for (int kk = 0; kk < 2; ++kk) {
      f16x8 av[4], bv[4];
#pragma unroll
      for (int m = 0; m < 4; ++m) {
        const int ra = wm * 64 + m * 16 + fr;
        av[m] = *(const f16x8*)&As[cur][ra * 64 + (((kk * 4 + fq) ^ (fr & 7)) << 3)];
      }
#pragma unroll
      for (int n = 0; n < 4; ++n) {
        const int rbw = wn * 64 + n * 16 + fr;
        bv[n] = *(const f16x8*)&Bs[cur][rbw * 64 + (((kk * 4 + fq) ^ (fr & 7)) << 3)];
      }
#pragma unroll
      for (int m = 0; m < 4; ++m)
#pragma unroll
        for (int n = 0; n < 4; ++n)
          acc[m][n] = __builtin_amdgcn_mfma_f32_16x16x32_f16(av[m], bv[n], acc[m][n], 0, 0, 0);
    }
    __syncthreads();         // single barrier per K-step (drains vmcnt too)
    cur ^= 1;
  }

  // C/D layout: col = lane&15, row = (lane>>4)*4 + reg  [m89 verified]
#pragma unroll
  for (int n = 0; n < 4; ++n) {
    const int col = col0 + wn * 64 + n * 16 + fr;
    const float bc = bias[e * N + col];
#pragma unroll
    for (int m = 0; m < 4; ++m) {
      const int rp = row0 + wm * 64 + m * 16 + fq * 4;
#pragma unroll
      for (int j = 0; j < 4; ++j) {
        if (rp + j < cnt) {
          float v = acc[m][n][j] + bc;
          if (RELU) v = fmaxf(v, 0.0f);
          Cdst[(size_t)(off + rp + j) * N + col] = (_Float16)v;
        }
      }
    }
  }
}

// ---------------------------------------------------------------------------
// expert layer 3 + gated scatter, 2-phase dbuf: tile 128x64 (N pad 50->64).
// ---------------------------------------------------------------------------
__global__ __launch_bounds__(256)
void expert_out(const _Float16* __restrict__ h2,    // [PADROWS][1024]
                const _Float16* __restrict__ Wt3,   // [E][64][1024]
                const float* __restrict__ eb3,      // [E][50]
                float* __restrict__ outp,           // [NTOK][50]
                const int* __restrict__ ctrl,
                const int* __restrict__ tokList,
                const float* __restrict__ gateList) {
  const int rb = blockIdx.y;
  if (rb >= ctrl[17]) return;
  int e = 0;
#pragma unroll
  for (int q = 1; q < 8; ++q) if (rb >= ctrl[9 + q]) e = q;
  const int cnt  = ctrl[e];
  const int off  = ctrl[18 + e];
  const int row0 = (rb - ctrl[9 + e]) * 128;

  __shared__ _Float16 As[2][128 * 64];
  __shared__ _Float16 Bs[2][64 * 64];

  const int tid = threadIdx.x;
  const int w = tid >> 6, l = tid & 63;
  const int fr = l & 15, fq = l >> 4;
  const int wm = w >> 1, wn = w & 1;

  const _Float16* aPtr[4];
  const _Float16* bPtr[2];
#pragma unroll
  for (int i = 0; i < 4; ++i) {
    const int s = i * 256 + tid;
    const int r = s >> 3, g = s & 7;
    aPtr[i] = h2 + (size_t)(off + row0 + r) * 1024 + (g ^ (r & 7)) * 8;
  }
#pragma unroll
  for (int i = 0; i < 2; ++i) {
    const int s = i * 256 + tid;
    const int r = s >> 3, g = s & 7;
    bPtr[i] = Wt3 + ((size_t)e * 64 + r) * 1024 + (g ^ (r & 7)) * 8;
  }

  auto STAGE = [&](int b, int k0) {
#pragma unroll
    for (int i = 0; i < 4; ++i)
      gload_lds16(aPtr[i] + k0, (void*)&As[b][(i * 256 + w * 64) * 8]);
#pragma unroll
    for (int i = 0; i < 2; ++i)
      gload_lds16(bPtr[i] + k0, (void*)&Bs[b][(i * 256 + w * 64) * 8]);
  };

  f32x4 acc[4][2];
#pragma unroll
  for (int m = 0; m < 4; ++m)
#pragma unroll
    for (int n = 0; n < 2; ++n) acc[m][n] = (f32x4)0.0f;

  constexpr int NT = 1024 / 64;
  STAGE(0, 0);
  __syncthreads();
  int cur = 0;
  for (int t = 0; t < NT; ++t) {
    if (t + 1 < NT) STAGE(cur ^ 1, (t + 1) * 64);
#pragma unroll
    for (int kk = 0; kk < 2; ++kk) {
      f16x8 av[4], bv[2];
#pragma unroll
      for (int m = 0; m < 4; ++m) {
        const int ra = wm * 64 + m * 16 + fr;
        av[m] = *(const f16x8*)&As[cur][ra * 64 + (((kk * 4 + fq) ^ (fr & 7)) << 3)];
      }
#pragma unroll
      for (int n = 0; n < 2; ++n) {
        const int rbw = wn * 32 + n * 16 + fr;
        bv[n] = *(const f16x8*)&Bs[cur][rbw * 64 + (((kk * 4 + fq) ^ (fr & 7)) << 3)];
      }
#pragma unroll
      for (int m = 0; m < 4; ++m)
#pragma unroll
        for (int n = 0; n < 2; ++n)
          acc[m][n] = __builtin_amdgcn_mfma_f32_16x16x32_f16(av[m], bv[n], acc[m][n], 0, 0, 0);
    }
    __syncthreads();
    cur ^= 1;
  }

#pragma unroll
  for (int m = 0; m < 4; ++m) {
    const int rp = row0 + wm * 64 + m * 16 + fq * 4;
#pragma unroll
    for (int j = 0; j < 4; ++j) {
      const int pos = rp + j;
      if (pos < cnt) {
        const int tok = tokList[e * CAP + pos];
        const float gate = gateList[e * CAP + pos];
#pragma unroll
        for (int n = 0; n < 2; ++n) {
          const int col = wn * 32 + n * 16 + fr;
          if (col < COUT) {
            const float v = acc[m][n][j] + eb3[e * COUT + col];
            atomicAdd(&outp[(size_t)tok * COUT + col], gate * v);
          }
        }
      }
    }
  }
}

// ---------------------------------------------------------------------------
extern "C" void kernel_launch(void* const* d_in, const int* in_sizes, int n_in,
                              void* d_out, int out_size, void* d_ws, size_t ws_size,
                              hipStream_t stream) {
  const float* x   = (const float*)d_in[0];
  const float* rW1 = (const float*)d_in[1];
  const float* rb1 = (const float*)d_in[2];
  const float* rW2 = (const float*)d_in[3];
  const float* rb2 = (const float*)d_in[4];
  const float* rW3 = (const float*)d_in[5];
  const float* rb3 = (const float*)d_in[6];
  const float* eW1 = (const float*)d_in[7];
  const float* eb1 = (const float*)d_in[8];
  const float* eW2 = (const float*)d_in[9];
  const float* eb2 = (const float*)d_in[10];
  const float* eW3 = (const float*)d_in[11];
  const float* eb3 = (const float*)d_in[12];

  float* outp  = (float*)d_out;                       // [16384][50]
  float* probs = outp + (size_t)NTOK * COUT;          // [16384][8]

  // ---- workspace carve with liveness unions (~245 MB) ----
  constexpr size_t SZ_X16 = (size_t)NTOK * DIM * 2;            // 33.55 MB
  constexpr size_t SZ_WT1 = (size_t)NEXP * H1 * DIM * 2;       // 33.55 MB
  constexpr size_t SZ_H2  = (size_t)PADROWS * H2 * 2;          // 69.6 MB
  constexpr size_t SZ_A   = (SZ_H2 > SZ_X16 + SZ_WT1) ? SZ_H2 : (SZ_X16 + SZ_WT1);
  constexpr size_t SZ_H1R = (size_t)NTOK * RH1 * 4;            // 33.55 MB
  constexpr size_t SZ_H2R = (size_t)NTOK * RH2 * 4;            // 16.78 MB
  constexpr size_t SZ_H1  = (size_t)PADROWS * H1 * 2;          // 139.2 MB
  constexpr size_t SZ_B   = (SZ_H1 > SZ_H1R + SZ_H2R) ? SZ_H1 : (SZ_H1R + SZ_H2R);

  char* p = (char*)d_ws;
  auto carve = [&](size_t bytes) {
    char* r = p;
    p += (bytes + 255) & ~(size_t)255;
    return r;
  };
  char* arenaA = carve(SZ_A);            // [x16 | Wt1]  ∪  h2
  char* arenaB = carve(SZ_B);            // [h1r | h2r]  ∪  h1
  _Float16* Wt2 = (_Float16*)carve((size_t)NEXP * H2 * H1 * 2);  // 33.55 MB
  _Float16* Wt3 = (_Float16*)carve((size_t)NEXP * 64 * H2 * 2);  // 1 MB
  int*   ctrl    = (int*)carve(256);
  int*   counts  = ctrl;
  int*   redoCnt = ctrl + 8;
  int*   sel     = (int*)carve((size_t)NTOK * 4);
  int*   redoList= (int*)carve((size_t)NTOK * 4);
  int*   tokList = (int*)carve((size_t)NEXP * CAP * 4);
  float* gateList= (float*)carve((size_t)NEXP * CAP * 4);

  _Float16* x16 = (_Float16*)arenaA;                 // live: conv .. expert L1
  _Float16* Wt1 = (_Float16*)(arenaA + SZ_X16);      // live: conv .. expert L1
  _Float16* h2  = (_Float16*)arenaA;                 // live: expert L2 .. L3
  float* h1r = (float*)arenaB;                       // live: router
  float* h2r = (float*)(arenaB + SZ_H1R);            // live: router
  _Float16* h1 = (_Float16*)arenaB;                  // live: expert L1 .. L2

  // ---- zero init ----
  zero_ctrl<<<1, 64, 0, stream>>>(ctrl);
  zero_out<<<800, 256, 0, stream>>>(outp);

  // ---- conversions ----
  cvt_f32_f16<<<(NTOK * DIM) / (256 * 4), 256, 0, stream>>>(x, x16, NTOK * DIM);
  cvtT<<<dim3(H1 / 32, DIM / 32, NEXP), 256, 0, stream>>>(eW1, Wt1, DIM, H1, H1);
  cvtT<<<dim3(H2 / 32, H1 / 32, NEXP), 256, 0, stream>>>(eW2, Wt2, H1, H2, H2);
  cvtT<<<dim3(64 / 32, H2 / 32, NEXP), 256, 0, stream>>>(eW3, Wt3, H2, COUT, 64);

  // ---- router ----
  sgemm_rt<true><<<dim3(RH1 / 64, NTOK / 128), 256, 0, stream>>>(x, rW1, rb1, h1r, NTOK, DIM, RH1);
  sgemm_rt<true><<<dim3(RH2 / 64, NTOK / 128), 256, 0, stream>>>(h1r, rW2, rb2, h2r, NTOK, RH1, RH2);
  router_score<<<NTOK / 256, 256, 0, stream>>>(h2r, rW3, rb3, probs, sel, redoList, redoCnt);
  router_redo<<<64, 256, 0, stream>>>(x, rW1, rb1, rW2, rb2, rW3, rb3, redoList, redoCnt, sel);
  build_lists<<<NTOK / 256, 256, 0, stream>>>(sel, probs, counts, tokList, gateList);
  scan_counts<<<1, 64, 0, stream>>>(ctrl);

  // ---- experts (fp16 MFMA, flattened padded row-block grids) ----
  expert_gemm<DIM, H1, true, true>
      <<<dim3(H1 / 128, MAXRB), 256, 0, stream>>>(x16, Wt1, eb1, h1, ctrl, tokList);
  expert_gemm<H1, H2, false, true>
      <<<dim3(H2 / 128, MAXRB), 256, 0, stream>>>(h1, Wt2, eb2, h2, ctrl, tokList);
  expert_out<<<dim3(1, MAXRB), 256, 0, stream>>>(h2, Wt3, eb3, outp, ctrl, tokList, gateList);

  (void)in_sizes; (void)n_in; (void)out_size; (void)ws_size;
}

// Round 8
// 1215.469 us; speedup vs baseline: 1.2105x; 1.1594x over previous
//
#include <hip/hip_runtime.h>
#include <cstdint>
#include <cstddef>

// ---------------------------------------------------------------------------
// MoE: router (fp16 MFMA + f64 ambiguity redo) -> top-2 lists -> expert MLP
// (fp16 MFMA, dual-barrier counted-vmcnt pipeline) -> gated scatter.
// B=16384, D=1024, E=8, C=50, RH=512/256, H1=2048, H2=1024, top_k=2
//
// R6 -> R7: fixed cross-wave race in counted-vmcnt pipeline. Correct phase:
//   STAGE(next); vmcnt(N own loads of CURRENT tile);  <- wait BEFORE barrier
//   s_barrier;          // all waves' current-tile loads landed (RAW)
//   ds_read + MFMA;
//   s_barrier;          // all reads done before buffer is re-staged (WAR)
// Next-tile loads stay in flight across both barriers (true T4).
// ---------------------------------------------------------------------------

typedef __attribute__((ext_vector_type(4))) float    f32x4;
typedef __attribute__((ext_vector_type(8))) _Float16 f16x8;
typedef __attribute__((ext_vector_type(4))) _Float16 f16x4;

#define DEVI __device__ __forceinline__

constexpr int NTOK = 16384;
constexpr int DIM  = 1024;
constexpr int NEXP = 8;
constexpr int COUT = 50;
constexpr int RH1  = 512;
constexpr int RH2  = 256;
constexpr int H1   = 2048;
constexpr int H2   = 1024;
constexpr int CAP  = NTOK;
constexpr int TOTROWS = 2 * NTOK;
constexpr int PADROWS = TOTROWS + NEXP * 128 + 128;
constexpr int MAXRB   = 264;

// ctrl ints: [0..7] counts, [8] redoCnt, [9..16] rbStart, [17] totRB, [18..25] offsP
DEVI void gload_lds16(const void* g, void* l) {
  auto gg = (const __attribute__((address_space(1))) uint32_t*)(uintptr_t)g;
  auto ll = (__attribute__((address_space(3))) uint32_t*)(uintptr_t)l;
  __builtin_amdgcn_global_load_lds(gg, ll, 16, 0, 0);
}

// BK=32 pair-packed swizzle. Logical (row r, 16B-granule kg in 0..3):
// r2=r>>1, g2=((r&1)<<2)|kg; physical 16B slot = r2*8 + (g2 ^ (r2&7)).
DEVI int swzIdx(int r, int kg) {
  const int r2 = r >> 1;
  const int g2 = ((r & 1) << 2) | kg;
  return (r2 * 8 + (g2 ^ (r2 & 7))) * 8;   // f16 element offset
}
// staging inverse: physical slot s -> logical (r, kg)
DEVI void swzInv(int s, int& r, int& kg) {
  const int r2 = s >> 3;
  const int g2 = (s & 7) ^ (r2 & 7);
  r  = r2 * 2 + (g2 >> 2);
  kg = g2 & 3;
}

// ---------------------------------------------------------------------------
__global__ void zero_ctrl(int* c) { if (threadIdx.x < 32) c[threadIdx.x] = 0; }

__global__ __launch_bounds__(256) void zero_out(float* __restrict__ o) {
  const int i = (blockIdx.x * 256 + threadIdx.x) * 4;
  if (i < NTOK * COUT) *(f32x4*)&o[i] = (f32x4)0.0f;
}

__global__ __launch_bounds__(256) void cvt_f32_f16(const float* __restrict__ in,
                                                   _Float16* __restrict__ out, int n) {
  int i = (blockIdx.x * 256 + threadIdx.x) * 4;
  if (i < n) {
    f32x4 v = *(const f32x4*)&in[i];
    f16x4 h;
    h[0] = (_Float16)v[0]; h[1] = (_Float16)v[1];
    h[2] = (_Float16)v[2]; h[3] = (_Float16)v[3];
    *(f16x4*)&out[i] = h;
  }
}

// transpose + convert: in [E][R][Cc] f32 -> out [E][Cpad][R] f16
__global__ __launch_bounds__(256) void cvtT(const float* __restrict__ in,
                                            _Float16* __restrict__ out,
                                            int R, int Cc, int Cpad) {
  __shared__ float tile[32][33];
  const int e = blockIdx.z;
  const float*  ip = in  + (size_t)e * R * Cc;
  _Float16*     op = out + (size_t)e * Cpad * R;
  const int tx = threadIdx.x & 31, ty = threadIdx.x >> 5;
  const int c = blockIdx.x * 32 + tx;
#pragma unroll
  for (int j = 0; j < 4; ++j) {
    const int r = blockIdx.y * 32 + ty + j * 8;
    tile[ty + j * 8][tx] = (c < Cc) ? ip[(size_t)r * Cc + c] : 0.0f;
  }
  __syncthreads();
  const int ocol = blockIdx.y * 32 + tx;
#pragma unroll
  for (int j = 0; j < 4; ++j) {
    const int orow = blockIdx.x * 32 + ty + j * 8;
    op[(size_t)orow * R + ocol] = (_Float16)tile[tx][ty + j * 8];
  }
}

// ---------------------------------------------------------------------------
// unified fp16 MFMA GEMM: C[rows,N] = act(A @ Wt^T + bias)
// tile 128x128, BK=32, dual-barrier counted-vmcnt pipeline, 4 waves, 4x4.
// MODE 0: dense (router). MODE 1: gather via tokList. MODE 2: compact rows.
// ---------------------------------------------------------------------------
template <int K, int N, int MODE, bool RELU, bool F32OUT>
__global__ __launch_bounds__(256)
void mfma_gemm(const _Float16* __restrict__ Asrc,
               const _Float16* __restrict__ Wt,     // [E][N][K]
               const float* __restrict__ bias,      // [E][N]
               void* __restrict__ CdstV,
               const int* __restrict__ ctrl,
               const int* __restrict__ tokList,
               int Mdense) {
  int e = 0, cnt, off = 0, row0;
  if (MODE == 0) {
    cnt = Mdense; row0 = blockIdx.y * 128;
  } else {
    const int rb = blockIdx.y;
    if (rb >= ctrl[17]) return;
#pragma unroll
    for (int q = 1; q < 8; ++q) if (rb >= ctrl[9 + q]) e = q;
    cnt = ctrl[e]; off = ctrl[18 + e]; row0 = (rb - ctrl[9 + e]) * 128;
  }
  const int col0 = blockIdx.x * 128;

  __shared__ _Float16 As[2][128 * 32];
  __shared__ _Float16 Bs[2][128 * 32];

  const int tid = threadIdx.x;
  const int w = tid >> 6, l = tid & 63;
  const int fr = l & 15, fq = l >> 4;
  const int wm = w >> 1, wn = w & 1;

  const _Float16* aPtr[2];
  const _Float16* bPtr[2];
#pragma unroll
  for (int i = 0; i < 2; ++i) {
    const int s = i * 256 + tid;
    int r, kg; swzInv(s, r, kg);
    int arow;
    if (MODE == 1) {
      int pos = row0 + r;
      pos = pos < cnt ? pos : cnt - 1;
      arow = tokList[e * CAP + pos];
    } else {
      arow = off + row0 + r;
    }
    aPtr[i] = Asrc + (size_t)arow * K + kg * 8;
    bPtr[i] = Wt + ((size_t)e * N + col0 + r) * K + kg * 8;
  }

  auto STAGE = [&](int b, int k0) {
#pragma unroll
    for (int i = 0; i < 2; ++i)
      gload_lds16(aPtr[i] + k0, (void*)&As[b][(i * 256 + w * 64) * 8]);
#pragma unroll
    for (int i = 0; i < 2; ++i)
      gload_lds16(bPtr[i] + k0, (void*)&Bs[b][(i * 256 + w * 64) * 8]);
  };

  int aOff[4], bOff[4];
#pragma unroll
  for (int m = 0; m < 4; ++m) aOff[m] = swzIdx(wm * 64 + m * 16 + fr, fq);
#pragma unroll
  for (int n = 0; n < 4; ++n) bOff[n] = swzIdx(wn * 64 + n * 16 + fr, fq);

  f32x4 acc[4][4];
#pragma unroll
  for (int m = 0; m < 4; ++m)
#pragma unroll
    for (int n = 0; n < 4; ++n) acc[m][n] = (f32x4)0.0f;

  constexpr int NT = K / 32;
  STAGE(0, 0);
  int cur = 0;
  for (int t = 0; t < NT; ++t) {
    // issue next tile, then wait for CURRENT tile's own loads, THEN barrier:
    // after the barrier every wave's current-tile loads have landed (RAW-safe).
    if (t + 1 < NT) {
      STAGE(cur ^ 1, (t + 1) * 32);
      asm volatile("s_waitcnt vmcnt(4)" ::: "memory");
    } else {
      asm volatile("s_waitcnt vmcnt(0)" ::: "memory");
    }
    __builtin_amdgcn_sched_barrier(0);
    __builtin_amdgcn_s_barrier();
    f16x8 av[4], bv[4];
#pragma unroll
    for (int m = 0; m < 4; ++m) av[m] = *(const f16x8*)&As[cur][aOff[m]];
#pragma unroll
    for (int n = 0; n < 4; ++n) bv[n] = *(const f16x8*)&Bs[cur][bOff[n]];
#pragma unroll
    for (int m = 0; m < 4; ++m)
#pragma unroll
      for (int n = 0; n < 4; ++n)
        acc[m][n] = __builtin_amdgcn_mfma_f32_16x16x32_f16(av[m], bv[n], acc[m][n], 0, 0, 0);
    __builtin_amdgcn_sched_barrier(0);
    __builtin_amdgcn_s_barrier();   // WAR: all reads of buf[cur] done
    cur ^= 1;
  }

  // C/D layout: col = lane&15, row = (lane>>4)*4 + reg  [m89 verified]
#pragma unroll
  for (int n = 0; n < 4; ++n) {
    const int col = col0 + wn * 64 + n * 16 + fr;
    const float bc = bias[e * N + col];
#pragma unroll
    for (int m = 0; m < 4; ++m) {
      const int rp = row0 + wm * 64 + m * 16 + fq * 4;
#pragma unroll
      for (int j = 0; j < 4; ++j) {
        if (rp + j < cnt) {
          float v = acc[m][n][j] + bc;
          if (RELU) v = fmaxf(v, 0.0f);
          if (F32OUT)
            ((float*)CdstV)[(size_t)(off + rp + j) * N + col] = v;
          else
            ((_Float16*)CdstV)[(size_t)(off + rp + j) * N + col] = (_Float16)v;
        }
      }
    }
  }
}

// ---------------------------------------------------------------------------
// expert layer 3 + gated scatter: tile 128x64 (N pad 50->64), BK=32 pipeline.
// ---------------------------------------------------------------------------
__global__ __launch_bounds__(256)
void expert_out(const _Float16* __restrict__ h2,    // [PADROWS][1024]
                const _Float16* __restrict__ Wt3,   // [E][64][1024]
                const float* __restrict__ eb3,      // [E][50]
                float* __restrict__ outp,           // [NTOK][50]
                const int* __restrict__ ctrl,
                const int* __restrict__ tokList,
                const float* __restrict__ gateList) {
  const int rb = blockIdx.y;
  if (rb >= ctrl[17]) return;
  int e = 0;
#pragma unroll
  for (int q = 1; q < 8; ++q) if (rb >= ctrl[9 + q]) e = q;
  const int cnt  = ctrl[e];
  const int off  = ctrl[18 + e];
  const int row0 = (rb - ctrl[9 + e]) * 128;

  __shared__ _Float16 As[2][128 * 32];
  __shared__ _Float16 Bs[2][64 * 32];

  const int tid = threadIdx.x;
  const int w = tid >> 6, l = tid & 63;
  const int fr = l & 15, fq = l >> 4;
  const int wm = w >> 1, wn = w & 1;

  const _Float16* aPtr[2];
  const _Float16* bPtr1;
#pragma unroll
  for (int i = 0; i < 2; ++i) {
    const int s = i * 256 + tid;
    int r, kg; swzInv(s, r, kg);
    aPtr[i] = h2 + (size_t)(off + row0 + r) * 1024 + kg * 8;
  }
  {
    int r, kg; swzInv(tid, r, kg);
    bPtr1 = Wt3 + ((size_t)e * 64 + r) * 1024 + kg * 8;
  }

  auto STAGE = [&](int b, int k0) {
#pragma unroll
    for (int i = 0; i < 2; ++i)
      gload_lds16(aPtr[i] + k0, (void*)&As[b][(i * 256 + w * 64) * 8]);
    gload_lds16(bPtr1 + k0, (void*)&Bs[b][(w * 64) * 8]);
  };

  int aOff[4], bOff[2];
#pragma unroll
  for (int m = 0; m < 4; ++m) aOff[m] = swzIdx(wm * 64 + m * 16 + fr, fq);
#pragma unroll
  for (int n = 0; n < 2; ++n) bOff[n] = swzIdx(wn * 32 + n * 16 + fr, fq);

  f32x4 acc[4][2];
#pragma unroll
  for (int m = 0; m < 4; ++m)
#pragma unroll
    for (int n = 0; n < 2; ++n) acc[m][n] = (f32x4)0.0f;

  constexpr int NT = 1024 / 32;
  STAGE(0, 0);
  int cur = 0;
  for (int t = 0; t < NT; ++t) {
    if (t + 1 < NT) {
      STAGE(cur ^ 1, (t + 1) * 32);
      asm volatile("s_waitcnt vmcnt(3)" ::: "memory");
    } else {
      asm volatile("s_waitcnt vmcnt(0)" ::: "memory");
    }
    __builtin_amdgcn_sched_barrier(0);
    __builtin_amdgcn_s_barrier();
    f16x8 av[4], bv[2];
#pragma unroll
    for (int m = 0; m < 4; ++m) av[m] = *(const f16x8*)&As[cur][aOff[m]];
#pragma unroll
    for (int n = 0; n < 2; ++n) bv[n] = *(const f16x8*)&Bs[cur][bOff[n]];
#pragma unroll
    for (int m = 0; m < 4; ++m)
#pragma unroll
      for (int n = 0; n < 2; ++n)
        acc[m][n] = __builtin_amdgcn_mfma_f32_16x16x32_f16(av[m], bv[n], acc[m][n], 0, 0, 0);
    __builtin_amdgcn_sched_barrier(0);
    __builtin_amdgcn_s_barrier();
    cur ^= 1;
  }

#pragma unroll
  for (int m = 0; m < 4; ++m) {
    const int rp = row0 + wm * 64 + m * 16 + fq * 4;
#pragma unroll
    for (int j = 0; j < 4; ++j) {
      const int pos = rp + j;
      if (pos < cnt) {
        const int tok = tokList[e * CAP + pos];
        const float gate = gateList[e * CAP + pos];
#pragma unroll
        for (int n = 0; n < 2; ++n) {
          const int col = wn * 32 + n * 16 + fr;
          if (col < COUT) {
            const float v = acc[m][n][j] + eb3[e * COUT + col];
            atomicAdd(&outp[(size_t)tok * COUT + col], gate * v);
          }
        }
      }
    }
  }
}

// ---------------------------------------------------------------------------
// router layer 3 + softmax + top-2 select; ambiguous rank2/3 -> f64 redo.
// ---------------------------------------------------------------------------
__global__ __launch_bounds__(256) void router_score(const float* __restrict__ h2r,
                                                    const float* __restrict__ rW3,
                                                    const float* __restrict__ rb3,
                                                    float* __restrict__ probs_out,
                                                    int* __restrict__ sel,
                                                    int* __restrict__ redoList,
                                                    int* __restrict__ redoCnt) {
  __shared__ float w3[256 * 8];
  __shared__ float tile[256 * 20];
  const int tid = threadIdx.x;
  const int t0 = blockIdx.x * 256;
  for (int i = tid; i < 256 * 8; i += 256) w3[i] = rW3[i];
  float acc[8];
#pragma unroll
  for (int e = 0; e < 8; ++e) acc[e] = 0.0f;

  for (int kc = 0; kc < RH2; kc += 16) {
    __syncthreads();
#pragma unroll
    for (int i = 0; i < 4; ++i) {
      const int r = (tid >> 2) + i * 64, q = tid & 3;
      const f32x4 v = *(const f32x4*)&h2r[(size_t)(t0 + r) * RH2 + kc + q * 4];
      *(f32x4*)&tile[r * 20 + q * 4] = v;
    }
    __syncthreads();
#pragma unroll
    for (int k = 0; k < 16; ++k) {
      const float hv = tile[tid * 20 + k];
#pragma unroll
      for (int e = 0; e < 8; ++e) acc[e] += hv * w3[(kc + k) * 8 + e];
    }
  }

  float s[8], mx = -1e30f;
#pragma unroll
  for (int e = 0; e < 8; ++e) { s[e] = acc[e] + rb3[e]; mx = fmaxf(mx, s[e]); }
  float p[8], sum = 0.0f;
#pragma unroll
  for (int e = 0; e < 8; ++e) { p[e] = expf(s[e] - mx); sum += p[e]; }
  const float inv = 1.0f / sum;
#pragma unroll
  for (int e = 0; e < 8; ++e) {
    p[e] *= inv;
    probs_out[(size_t)(t0 + tid) * 8 + e] = p[e];
  }
  int i1 = 0;
#pragma unroll
  for (int e = 1; e < 8; ++e) if (s[e] > s[i1]) i1 = e;
  int i2 = (i1 == 0) ? 1 : 0;
#pragma unroll
  for (int e = 0; e < 8; ++e) if (e != i1 && s[e] > s[i2]) i2 = e;
  int i3 = -1;
#pragma unroll
  for (int e = 0; e < 8; ++e)
    if (e != i1 && e != i2 && (i3 < 0 || s[e] > s[i3])) i3 = e;

  const int tok = t0 + tid;
  sel[tok] = i1 * 8 + i2;
  if (s[i2] - s[i3] < 6e-3f) {   // fp16-router ambiguity window (~8 sigma)
    const int pos = atomicAdd(redoCnt, 1);
    redoList[pos] = tok;
  }
}

// exact (f64) router recompute for ambiguous tokens; one block per token.
__global__ __launch_bounds__(256)
void router_redo(const float* __restrict__ x,
                 const float* __restrict__ rW1, const float* __restrict__ rb1,
                 const float* __restrict__ rW2, const float* __restrict__ rb2,
                 const float* __restrict__ rW3, const float* __restrict__ rb3,
                 const int* __restrict__ redoList, const int* __restrict__ redoCnt,
                 int* __restrict__ sel) {
  __shared__ double sh1[512];
  __shared__ double sh2[256];
  __shared__ double sred[256];
  const int tid = threadIdx.x;
  const int n = *redoCnt;
  for (int it = blockIdx.x; it < n; it += gridDim.x) {
    const int tok = redoList[it];
    const float* xr = x + (size_t)tok * DIM;
#pragma unroll
    for (int c = 0; c < 2; ++c) {
      const int nn = c * 256 + tid;
      double a = (double)rb1[nn];
      for (int k = 0; k < DIM; ++k)
        a += (double)xr[k] * (double)rW1[(size_t)k * RH1 + nn];
      sh1[nn] = a > 0.0 ? a : 0.0;
    }
    __syncthreads();
    {
      double a = (double)rb2[tid];
      for (int k = 0; k < RH1; ++k)
        a += sh1[k] * (double)rW2[(size_t)k * RH2 + tid];
      sh2[tid] = a > 0.0 ? a : 0.0;
    }
    __syncthreads();
    {
      const int e = tid >> 5;
      double a = 0.0;
      for (int k = tid & 31; k < RH2; k += 32)
        a += sh2[k] * (double)rW3[(size_t)k * 8 + e];
      sred[tid] = a;
    }
    __syncthreads();
    if (tid < 8) {
      double s = (double)rb3[tid];
      for (int j = 0; j < 32; ++j) s += sred[tid * 32 + j];
      sred[tid] = s;
    }
    __syncthreads();
    if (tid == 0) {
      double s[8];
#pragma unroll
      for (int e = 0; e < 8; ++e) s[e] = sred[e];
      int i1 = 0;
      for (int e = 1; e < 8; ++e) if (s[e] > s[i1]) i1 = e;
      int i2 = (i1 == 0) ? 1 : 0;
      for (int e = 0; e < 8; ++e) if (e != i1 && s[e] > s[i2]) i2 = e;
      sel[tok] = i1 * 8 + i2;
    }
    __syncthreads();
  }
}

// ---------------------------------------------------------------------------
__global__ __launch_bounds__(256)
void build_lists(const int* __restrict__ sel, const float* __restrict__ probs,
                 int* __restrict__ counts, int* __restrict__ tokList,
                 float* __restrict__ gateList) {
  const int tok = blockIdx.x * 256 + threadIdx.x;
  const int sl = sel[tok];
  const int e1 = sl >> 3, e2 = sl & 7;
  const float p1 = probs[(size_t)tok * 8 + e1] * 0.5f;
  const float p2 = probs[(size_t)tok * 8 + e2] * 0.5f;
  int pos = atomicAdd(&counts[e1], 1);
  tokList[e1 * CAP + pos] = tok; gateList[e1 * CAP + pos] = p1;
  pos = atomicAdd(&counts[e2], 1);
  tokList[e2 * CAP + pos] = tok; gateList[e2 * CAP + pos] = p2;
}

__global__ void scan_counts(int* __restrict__ ctrl) {
  if (threadIdx.x == 0 && blockIdx.x == 0) {
    int rb = 0, s = 0;
    for (int e = 0; e < NEXP; ++e) {
      ctrl[9 + e]  = rb;
      ctrl[18 + e] = s;
      const int nrb = (ctrl[e] + 127) >> 7;
      rb += nrb; s += nrb * 128;
    }
    ctrl[17] = rb;
  }
}

// ---------------------------------------------------------------------------
extern "C" void kernel_launch(void* const* d_in, const int* in_sizes, int n_in,
                              void* d_out, int out_size, void* d_ws, size_t ws_size,
                              hipStream_t stream) {
  const float* x   = (const float*)d_in[0];
  const float* rW1 = (const float*)d_in[1];
  const float* rb1 = (const float*)d_in[2];
  const float* rW2 = (const float*)d_in[3];
  const float* rb2 = (const float*)d_in[4];
  const float* rW3 = (const float*)d_in[5];
  const float* rb3 = (const float*)d_in[6];
  const float* eW1 = (const float*)d_in[7];
  const float* eb1 = (const float*)d_in[8];
  const float* eW2 = (const float*)d_in[9];
  const float* eb2 = (const float*)d_in[10];
  const float* eW3 = (const float*)d_in[11];
  const float* eb3 = (const float*)d_in[12];

  float* outp  = (float*)d_out;                       // [16384][50]
  float* probs = outp + (size_t)NTOK * COUT;          // [16384][8]

  // ---- workspace carve with liveness unions (~248 MB) ----
  constexpr size_t SZ_X16  = (size_t)NTOK * DIM * 2;            // 33.55 MB
  constexpr size_t SZ_WT1  = (size_t)NEXP * H1 * DIM * 2;       // 33.55 MB
  constexpr size_t SZ_H2   = (size_t)PADROWS * H2 * 2;          // 69.5 MB
  constexpr size_t SZ_A    = (SZ_H2 > SZ_X16 + SZ_WT1) ? SZ_H2 : (SZ_X16 + SZ_WT1);
  constexpr size_t SZ_H1R16 = (size_t)NTOK * RH1 * 2;           // 16.78 MB
  constexpr size_t SZ_H2R32 = (size_t)NTOK * RH2 * 4;           // 16.78 MB
  constexpr size_t SZ_H1   = (size_t)PADROWS * H1 * 2;          // 139 MB
  constexpr size_t SZ_B    = (SZ_H1 > SZ_H1R16 + SZ_H2R32) ? SZ_H1 : (SZ_H1R16 + SZ_H2R32);

  char* p = (char*)d_ws;
  auto carve = [&](size_t bytes) {
    char* r = p;
    p += (bytes + 255) & ~(size_t)255;
    return r;
  };
  char* arenaA = carve(SZ_A);            // [x16 | Wt1]  U  h2
  char* arenaB = carve(SZ_B);            // [h1r16 | h2r32]  U  h1
  _Float16* Wt2  = (_Float16*)carve((size_t)NEXP * H2 * H1 * 2);  // 33.55 MB
  _Float16* Wt3  = (_Float16*)carve((size_t)NEXP * 64 * H2 * 2);  // 1 MB
  _Float16* rWt1 = (_Float16*)carve((size_t)RH1 * DIM * 2);       // 1 MB
  _Float16* rWt2 = (_Float16*)carve((size_t)RH2 * RH1 * 2);       // 0.26 MB
  int*   ctrl    = (int*)carve(256);
  int*   counts  = ctrl;
  int*   redoCnt = ctrl + 8;
  int*   sel     = (int*)carve((size_t)NTOK * 4);
  int*   redoList= (int*)carve((size_t)NTOK * 4);
  int*   tokList = (int*)carve((size_t)NEXP * CAP * 4);
  float* gateList= (float*)carve((size_t)NEXP * CAP * 4);

  _Float16* x16   = (_Float16*)arenaA;               // live: conv .. expert L1
  _Float16* Wt1   = (_Float16*)(arenaA + SZ_X16);    // live: conv .. expert L1
  _Float16* h2    = (_Float16*)arenaA;               // live: expert L2 .. L3
  _Float16* h1r16 = (_Float16*)arenaB;               // live: router L1 .. L2
  float*    h2r   = (float*)(arenaB + SZ_H1R16);     // live: router L2 .. score
  _Float16* h1    = (_Float16*)arenaB;               // live: expert L1 .. L2

  // ---- zero init ----
  zero_ctrl<<<1, 64, 0, stream>>>(ctrl);
  zero_out<<<800, 256, 0, stream>>>(outp);

  // ---- conversions ----
  cvt_f32_f16<<<(NTOK * DIM) / (256 * 4), 256, 0, stream>>>(x, x16, NTOK * DIM);
  cvtT<<<dim3(H1 / 32, DIM / 32, NEXP), 256, 0, stream>>>(eW1, Wt1, DIM, H1, H1);
  cvtT<<<dim3(H2 / 32, H1 / 32, NEXP), 256, 0, stream>>>(eW2, Wt2, H1, H2, H2);
  cvtT<<<dim3(64 / 32, H2 / 32, NEXP), 256, 0, stream>>>(eW3, Wt3, H2, COUT, 64);
  cvtT<<<dim3(RH1 / 32, DIM / 32, 1), 256, 0, stream>>>(rW1, rWt1, DIM, RH1, RH1);
  cvtT<<<dim3(RH2 / 32, RH1 / 32, 1), 256, 0, stream>>>(rW2, rWt2, RH1, RH2, RH2);

  // ---- router (fp16 MFMA; fp64 redo covers ranking ambiguity) ----
  mfma_gemm<DIM, RH1, 0, true, false>
      <<<dim3(RH1 / 128, NTOK / 128), 256, 0, stream>>>(x16, rWt1, rb1, h1r16, nullptr, nullptr, NTOK);
  mfma_gemm<RH1, RH2, 0, true, true>
      <<<dim3(RH2 / 128, NTOK / 128), 256, 0, stream>>>(h1r16, rWt2, rb2, h2r, nullptr, nullptr, NTOK);
  router_score<<<NTOK / 256, 256, 0, stream>>>(h2r, rW3, rb3, probs, sel, redoList, redoCnt);
  router_redo<<<256, 256, 0, stream>>>(x, rW1, rb1, rW2, rb2, rW3, rb3, redoList, redoCnt, sel);
  build_lists<<<NTOK / 256, 256, 0, stream>>>(sel, probs, counts, tokList, gateList);
  scan_counts<<<1, 64, 0, stream>>>(ctrl);

  // ---- experts (fp16 MFMA, flattened padded row-block grids) ----
  mfma_gemm<DIM, H1, 1, true, false>
      <<<dim3(H1 / 128, MAXRB), 256, 0, stream>>>(x16, Wt1, eb1, h1, ctrl, tokList, 0);
  mfma_gemm<H1, H2, 2, true, false>
      <<<dim3(H2 / 128, MAXRB), 256, 0, stream>>>(h1, Wt2, eb2, h2, ctrl, tokList, 0);
  expert_out<<<dim3(1, MAXRB), 256, 0, stream>>>(h2, Wt3, eb3, outp, ctrl, tokList, gateList);

  (void)in_sizes; (void)n_in; (void)out_size; (void)ws_size;
}

// Round 10
// 1072.464 us; speedup vs baseline: 1.3719x; 1.1333x over previous
//
#include <hip/hip_runtime.h>
#include <cstdint>
#include <cstddef>

// ---------------------------------------------------------------------------
// MoE: router (fp16 MFMA + f64 ambiguity redo) -> top-2 lists -> expert MLP
// (fp16 MFMA, dual-barrier counted-vmcnt pipeline) -> gated scatter.
// B=16384, D=1024, E=8, C=50, RH=512/256, H1=2048, H2=1024, top_k=2
//
// R8 -> R9: router_redo was 248us (20% of total): single-accumulator serial
// f64 chain = 1 load in flight, ~200cyc stall per k. Fix: 4 independent
// accumulators + x staged in LDS + grid 512. Everything else unchanged from
// the R8-passing kernel.
// ---------------------------------------------------------------------------

typedef __attribute__((ext_vector_type(4))) float    f32x4;
typedef __attribute__((ext_vector_type(8))) _Float16 f16x8;
typedef __attribute__((ext_vector_type(4))) _Float16 f16x4;

#define DEVI __device__ __forceinline__

constexpr int NTOK = 16384;
constexpr int DIM  = 1024;
constexpr int NEXP = 8;
constexpr int COUT = 50;
constexpr int RH1  = 512;
constexpr int RH2  = 256;
constexpr int H1   = 2048;
constexpr int H2   = 1024;
constexpr int CAP  = NTOK;
constexpr int TOTROWS = 2 * NTOK;
constexpr int PADROWS = TOTROWS + NEXP * 128 + 128;
constexpr int MAXRB   = 264;

// ctrl ints: [0..7] counts, [8] redoCnt, [9..16] rbStart, [17] totRB, [18..25] offsP
DEVI void gload_lds16(const void* g, void* l) {
  auto gg = (const __attribute__((address_space(1))) uint32_t*)(uintptr_t)g;
  auto ll = (__attribute__((address_space(3))) uint32_t*)(uintptr_t)l;
  __builtin_amdgcn_global_load_lds(gg, ll, 16, 0, 0);
}

// BK=32 pair-packed swizzle. Logical (row r, 16B-granule kg in 0..3):
// r2=r>>1, g2=((r&1)<<2)|kg; physical 16B slot = r2*8 + (g2 ^ (r2&7)).
DEVI int swzIdx(int r, int kg) {
  const int r2 = r >> 1;
  const int g2 = ((r & 1) << 2) | kg;
  return (r2 * 8 + (g2 ^ (r2 & 7))) * 8;   // f16 element offset
}
// staging inverse: physical slot s -> logical (r, kg)
DEVI void swzInv(int s, int& r, int& kg) {
  const int r2 = s >> 3;
  const int g2 = (s & 7) ^ (r2 & 7);
  r  = r2 * 2 + (g2 >> 2);
  kg = g2 & 3;
}

// ---------------------------------------------------------------------------
__global__ void zero_ctrl(int* c) { if (threadIdx.x < 32) c[threadIdx.x] = 0; }

__global__ __launch_bounds__(256) void zero_out(float* __restrict__ o) {
  const int i = (blockIdx.x * 256 + threadIdx.x) * 4;
  if (i < NTOK * COUT) *(f32x4*)&o[i] = (f32x4)0.0f;
}

__global__ __launch_bounds__(256) void cvt_f32_f16(const float* __restrict__ in,
                                                   _Float16* __restrict__ out, int n) {
  int i = (blockIdx.x * 256 + threadIdx.x) * 4;
  if (i < n) {
    f32x4 v = *(const f32x4*)&in[i];
    f16x4 h;
    h[0] = (_Float16)v[0]; h[1] = (_Float16)v[1];
    h[2] = (_Float16)v[2]; h[3] = (_Float16)v[3];
    *(f16x4*)&out[i] = h;
  }
}

// transpose + convert: in [E][R][Cc] f32 -> out [E][Cpad][R] f16
__global__ __launch_bounds__(256) void cvtT(const float* __restrict__ in,
                                            _Float16* __restrict__ out,
                                            int R, int Cc, int Cpad) {
  __shared__ float tile[32][33];
  const int e = blockIdx.z;
  const float*  ip = in  + (size_t)e * R * Cc;
  _Float16*     op = out + (size_t)e * Cpad * R;
  const int tx = threadIdx.x & 31, ty = threadIdx.x >> 5;
  const int c = blockIdx.x * 32 + tx;
#pragma unroll
  for (int j = 0; j < 4; ++j) {
    const int r = blockIdx.y * 32 + ty + j * 8;
    tile[ty + j * 8][tx] = (c < Cc) ? ip[(size_t)r * Cc + c] : 0.0f;
  }
  __syncthreads();
  const int ocol = blockIdx.y * 32 + tx;
#pragma unroll
  for (int j = 0; j < 4; ++j) {
    const int orow = blockIdx.x * 32 + ty + j * 8;
    op[(size_t)orow * R + ocol] = (_Float16)tile[tx][ty + j * 8];
  }
}

// ---------------------------------------------------------------------------
// unified fp16 MFMA GEMM: C[rows,N] = act(A @ Wt^T + bias)
// tile 128x128, BK=32, dual-barrier counted-vmcnt pipeline, 4 waves, 4x4.
// MODE 0: dense (router). MODE 1: gather via tokList. MODE 2: compact rows.
// ---------------------------------------------------------------------------
template <int K, int N, int MODE, bool RELU, bool F32OUT>
__global__ __launch_bounds__(256)
void mfma_gemm(const _Float16* __restrict__ Asrc,
               const _Float16* __restrict__ Wt,     // [E][N][K]
               const float* __restrict__ bias,      // [E][N]
               void* __restrict__ CdstV,
               const int* __restrict__ ctrl,
               const int* __restrict__ tokList,
               int Mdense) {
  int e = 0, cnt, off = 0, row0;
  if (MODE == 0) {
    cnt = Mdense; row0 = blockIdx.y * 128;
  } else {
    const int rb = blockIdx.y;
    if (rb >= ctrl[17]) return;
#pragma unroll
    for (int q = 1; q < 8; ++q) if (rb >= ctrl[9 + q]) e = q;
    cnt = ctrl[e]; off = ctrl[18 + e]; row0 = (rb - ctrl[9 + e]) * 128;
  }
  const int col0 = blockIdx.x * 128;

  __shared__ _Float16 As[2][128 * 32];
  __shared__ _Float16 Bs[2][128 * 32];

  const int tid = threadIdx.x;
  const int w = tid >> 6, l = tid & 63;
  const int fr = l & 15, fq = l >> 4;
  const int wm = w >> 1, wn = w & 1;

  const _Float16* aPtr[2];
  const _Float16* bPtr[2];
#pragma unroll
  for (int i = 0; i < 2; ++i) {
    const int s = i * 256 + tid;
    int r, kg; swzInv(s, r, kg);
    int arow;
    if (MODE == 1) {
      int pos = row0 + r;
      pos = pos < cnt ? pos : cnt - 1;
      arow = tokList[e * CAP + pos];
    } else {
      arow = off + row0 + r;
    }
    aPtr[i] = Asrc + (size_t)arow * K + kg * 8;
    bPtr[i] = Wt + ((size_t)e * N + col0 + r) * K + kg * 8;
  }

  auto STAGE = [&](int b, int k0) {
#pragma unroll
    for (int i = 0; i < 2; ++i)
      gload_lds16(aPtr[i] + k0, (void*)&As[b][(i * 256 + w * 64) * 8]);
#pragma unroll
    for (int i = 0; i < 2; ++i)
      gload_lds16(bPtr[i] + k0, (void*)&Bs[b][(i * 256 + w * 64) * 8]);
  };

  int aOff[4], bOff[4];
#pragma unroll
  for (int m = 0; m < 4; ++m) aOff[m] = swzIdx(wm * 64 + m * 16 + fr, fq);
#pragma unroll
  for (int n = 0; n < 4; ++n) bOff[n] = swzIdx(wn * 64 + n * 16 + fr, fq);

  f32x4 acc[4][4];
#pragma unroll
  for (int m = 0; m < 4; ++m)
#pragma unroll
    for (int n = 0; n < 4; ++n) acc[m][n] = (f32x4)0.0f;

  constexpr int NT = K / 32;
  STAGE(0, 0);
  int cur = 0;
  for (int t = 0; t < NT; ++t) {
    // issue next tile, then wait for CURRENT tile's own loads, THEN barrier:
    // after the barrier every wave's current-tile loads have landed (RAW-safe).
    if (t + 1 < NT) {
      STAGE(cur ^ 1, (t + 1) * 32);
      asm volatile("s_waitcnt vmcnt(4)" ::: "memory");
    } else {
      asm volatile("s_waitcnt vmcnt(0)" ::: "memory");
    }
    __builtin_amdgcn_sched_barrier(0);
    __builtin_amdgcn_s_barrier();
    f16x8 av[4], bv[4];
#pragma unroll
    for (int m = 0; m < 4; ++m) av[m] = *(const f16x8*)&As[cur][aOff[m]];
#pragma unroll
    for (int n = 0; n < 4; ++n) bv[n] = *(const f16x8*)&Bs[cur][bOff[n]];
#pragma unroll
    for (int m = 0; m < 4; ++m)
#pragma unroll
      for (int n = 0; n < 4; ++n)
        acc[m][n] = __builtin_amdgcn_mfma_f32_16x16x32_f16(av[m], bv[n], acc[m][n], 0, 0, 0);
    __builtin_amdgcn_sched_barrier(0);
    __builtin_amdgcn_s_barrier();   // WAR: all reads of buf[cur] done
    cur ^= 1;
  }

  // C/D layout: col = lane&15, row = (lane>>4)*4 + reg  [m89 verified]
#pragma unroll
  for (int n = 0; n < 4; ++n) {
    const int col = col0 + wn * 64 + n * 16 + fr;
    const float bc = bias[e * N + col];
#pragma unroll
    for (int m = 0; m < 4; ++m) {
      const int rp = row0 + wm * 64 + m * 16 + fq * 4;
#pragma unroll
      for (int j = 0; j < 4; ++j) {
        if (rp + j < cnt) {
          float v = acc[m][n][j] + bc;
          if (RELU) v = fmaxf(v, 0.0f);
          if (F32OUT)
            ((float*)CdstV)[(size_t)(off + rp + j) * N + col] = v;
          else
            ((_Float16*)CdstV)[(size_t)(off + rp + j) * N + col] = (_Float16)v;
        }
      }
    }
  }
}

// ---------------------------------------------------------------------------
// expert layer 3 + gated scatter: tile 128x64 (N pad 50->64), BK=32 pipeline.
// ---------------------------------------------------------------------------
__global__ __launch_bounds__(256)
void expert_out(const _Float16* __restrict__ h2,    // [PADROWS][1024]
                const _Float16* __restrict__ Wt3,   // [E][64][1024]
                const float* __restrict__ eb3,      // [E][50]
                float* __restrict__ outp,           // [NTOK][50]
                const int* __restrict__ ctrl,
                const int* __restrict__ tokList,
                const float* __restrict__ gateList) {
  const int rb = blockIdx.y;
  if (rb >= ctrl[17]) return;
  int e = 0;
#pragma unroll
  for (int q = 1; q < 8; ++q) if (rb >= ctrl[9 + q]) e = q;
  const int cnt  = ctrl[e];
  const int off  = ctrl[18 + e];
  const int row0 = (rb - ctrl[9 + e]) * 128;

  __shared__ _Float16 As[2][128 * 32];
  __shared__ _Float16 Bs[2][64 * 32];

  const int tid = threadIdx.x;
  const int w = tid >> 6, l = tid & 63;
  const int fr = l & 15, fq = l >> 4;
  const int wm = w >> 1, wn = w & 1;

  const _Float16* aPtr[2];
  const _Float16* bPtr1;
#pragma unroll
  for (int i = 0; i < 2; ++i) {
    const int s = i * 256 + tid;
    int r, kg; swzInv(s, r, kg);
    aPtr[i] = h2 + (size_t)(off + row0 + r) * 1024 + kg * 8;
  }
  {
    int r, kg; swzInv(tid, r, kg);
    bPtr1 = Wt3 + ((size_t)e * 64 + r) * 1024 + kg * 8;
  }

  auto STAGE = [&](int b, int k0) {
#pragma unroll
    for (int i = 0; i < 2; ++i)
      gload_lds16(aPtr[i] + k0, (void*)&As[b][(i * 256 + w * 64) * 8]);
    gload_lds16(bPtr1 + k0, (void*)&Bs[b][(w * 64) * 8]);
  };

  int aOff[4], bOff[2];
#pragma unroll
  for (int m = 0; m < 4; ++m) aOff[m] = swzIdx(wm * 64 + m * 16 + fr, fq);
#pragma unroll
  for (int n = 0; n < 2; ++n) bOff[n] = swzIdx(wn * 32 + n * 16 + fr, fq);

  f32x4 acc[4][2];
#pragma unroll
  for (int m = 0; m < 4; ++m)
#pragma unroll
    for (int n = 0; n < 2; ++n) acc[m][n] = (f32x4)0.0f;

  constexpr int NT = 1024 / 32;
  STAGE(0, 0);
  int cur = 0;
  for (int t = 0; t < NT; ++t) {
    if (t + 1 < NT) {
      STAGE(cur ^ 1, (t + 1) * 32);
      asm volatile("s_waitcnt vmcnt(3)" ::: "memory");
    } else {
      asm volatile("s_waitcnt vmcnt(0)" ::: "memory");
    }
    __builtin_amdgcn_sched_barrier(0);
    __builtin_amdgcn_s_barrier();
    f16x8 av[4], bv[2];
#pragma unroll
    for (int m = 0; m < 4; ++m) av[m] = *(const f16x8*)&As[cur][aOff[m]];
#pragma unroll
    for (int n = 0; n < 2; ++n) bv[n] = *(const f16x8*)&Bs[cur][bOff[n]];
#pragma unroll
    for (int m = 0; m < 4; ++m)
#pragma unroll
      for (int n = 0; n < 2; ++n)
        acc[m][n] = __builtin_amdgcn_mfma_f32_16x16x32_f16(av[m], bv[n], acc[m][n], 0, 0, 0);
    __builtin_amdgcn_sched_barrier(0);
    __builtin_amdgcn_s_barrier();
    cur ^= 1;
  }

#pragma unroll
  for (int m = 0; m < 4; ++m) {
    const int rp = row0 + wm * 64 + m * 16 + fq * 4;
#pragma unroll
    for (int j = 0; j < 4; ++j) {
      const int pos = rp + j;
      if (pos < cnt) {
        const int tok = tokList[e * CAP + pos];
        const float gate = gateList[e * CAP + pos];
#pragma unroll
        for (int n = 0; n < 2; ++n) {
          const int col = wn * 32 + n * 16 + fr;
          if (col < COUT) {
            const float v = acc[m][n][j] + eb3[e * COUT + col];
            atomicAdd(&outp[(size_t)tok * COUT + col], gate * v);
          }
        }
      }
    }
  }
}

// ---------------------------------------------------------------------------
// router layer 3 + softmax + top-2 select; ambiguous rank2/3 -> f64 redo.
// ---------------------------------------------------------------------------
__global__ __launch_bounds__(256) void router_score(const float* __restrict__ h2r,
                                                    const float* __restrict__ rW3,
                                                    const float* __restrict__ rb3,
                                                    float* __restrict__ probs_out,
                                                    int* __restrict__ sel,
                                                    int* __restrict__ redoList,
                                                    int* __restrict__ redoCnt) {
  __shared__ float w3[256 * 8];
  __shared__ float tile[256 * 20];
  const int tid = threadIdx.x;
  const int t0 = blockIdx.x * 256;
  for (int i = tid; i < 256 * 8; i += 256) w3[i] = rW3[i];
  float acc[8];
#pragma unroll
  for (int e = 0; e < 8; ++e) acc[e] = 0.0f;

  for (int kc = 0; kc < RH2; kc += 16) {
    __syncthreads();
#pragma unroll
    for (int i = 0; i < 4; ++i) {
      const int r = (tid >> 2) + i * 64, q = tid & 3;
      const f32x4 v = *(const f32x4*)&h2r[(size_t)(t0 + r) * RH2 + kc + q * 4];
      *(f32x4*)&tile[r * 20 + q * 4] = v;
    }
    __syncthreads();
#pragma unroll
    for (int k = 0; k < 16; ++k) {
      const float hv = tile[tid * 20 + k];
#pragma unroll
      for (int e = 0; e < 8; ++e) acc[e] += hv * w3[(kc + k) * 8 + e];
    }
  }

  float s[8], mx = -1e30f;
#pragma unroll
  for (int e = 0; e < 8; ++e) { s[e] = acc[e] + rb3[e]; mx = fmaxf(mx, s[e]); }
  float p[8], sum = 0.0f;
#pragma unroll
  for (int e = 0; e < 8; ++e) { p[e] = expf(s[e] - mx); sum += p[e]; }
  const float inv = 1.0f / sum;
#pragma unroll
  for (int e = 0; e < 8; ++e) {
    p[e] *= inv;
    probs_out[(size_t)(t0 + tid) * 8 + e] = p[e];
  }
  int i1 = 0;
#pragma unroll
  for (int e = 1; e < 8; ++e) if (s[e] > s[i1]) i1 = e;
  int i2 = (i1 == 0) ? 1 : 0;
#pragma unroll
  for (int e = 0; e < 8; ++e) if (e != i1 && s[e] > s[i2]) i2 = e;
  int i3 = -1;
#pragma unroll
  for (int e = 0; e < 8; ++e)
    if (e != i1 && e != i2 && (i3 < 0 || s[e] > s[i3])) i3 = e;

  const int tok = t0 + tid;
  sel[tok] = i1 * 8 + i2;
  if (s[i2] - s[i3] < 6e-3f) {   // fp16-router ambiguity window (~8 sigma)
    const int pos = atomicAdd(redoCnt, 1);
    redoList[pos] = tok;
  }
}

// exact (f64) router recompute for ambiguous tokens; one block per token.
// 4 independent accumulators per neuron (loads stay in flight), x in LDS.
__global__ __launch_bounds__(256)
void router_redo(const float* __restrict__ x,
                 const float* __restrict__ rW1, const float* __restrict__ rb1,
                 const float* __restrict__ rW2, const float* __restrict__ rb2,
                 const float* __restrict__ rW3, const float* __restrict__ rb3,
                 const int* __restrict__ redoList, const int* __restrict__ redoCnt,
                 int* __restrict__ sel) {
  __shared__ float  sx[DIM];
  __shared__ double sh1[512];
  __shared__ double sh2[256];
  __shared__ double sred[256];
  const int tid = threadIdx.x;
  const int n = *redoCnt;
  for (int it = blockIdx.x; it < n; it += gridDim.x) {
    const int tok = redoList[it];
    const float* xr = x + (size_t)tok * DIM;
    for (int k = tid; k < DIM; k += 256) sx[k] = xr[k];
    __syncthreads();
#pragma unroll
    for (int c = 0; c < 2; ++c) {
      const int nn = c * 256 + tid;
      double a0 = 0.0, a1 = 0.0, a2 = 0.0, a3 = 0.0;
      for (int k = 0; k < DIM; k += 4) {
        a0 += (double)sx[k + 0] * (double)rW1[(size_t)(k + 0) * RH1 + nn];
        a1 += (double)sx[k + 1] * (double)rW1[(size_t)(k + 1) * RH1 + nn];
        a2 += (double)sx[k + 2] * (double)rW1[(size_t)(k + 2) * RH1 + nn];
        a3 += (double)sx[k + 3] * (double)rW1[(size_t)(k + 3) * RH1 + nn];
      }
      const double a = ((a0 + a1) + (a2 + a3)) + (double)rb1[nn];
      sh1[nn] = a > 0.0 ? a : 0.0;
    }
    __syncthreads();
    {
      double a0 = 0.0, a1 = 0.0, a2 = 0.0, a3 = 0.0;
      for (int k = 0; k < RH1; k += 4) {
        a0 += sh1[k + 0] * (double)rW2[(size_t)(k + 0) * RH2 + tid];
        a1 += sh1[k + 1] * (double)rW2[(size_t)(k + 1) * RH2 + tid];
        a2 += sh1[k + 2] * (double)rW2[(size_t)(k + 2) * RH2 + tid];
        a3 += sh1[k + 3] * (double)rW2[(size_t)(k + 3) * RH2 + tid];
      }
      const double a = ((a0 + a1) + (a2 + a3)) + (double)rb2[tid];
      sh2[tid] = a > 0.0 ? a : 0.0;
    }
    __syncthreads();
    {
      const int e = tid >> 5;
      double a = 0.0;
      for (int k = tid & 31; k < RH2; k += 32)
        a += sh2[k] * (double)rW3[(size_t)k * 8 + e];
      sred[tid] = a;
    }
    __syncthreads();
    if (tid < 8) {
      double s = (double)rb3[tid];
      for (int j = 0; j < 32; ++j) s += sred[tid * 32 + j];
      sred[tid] = s;
    }
    __syncthreads();
    if (tid == 0) {
      double s[8];
#pragma unroll
      for (int e = 0; e < 8; ++e) s[e] = sred[e];
      int i1 = 0;
      for (int e = 1; e < 8; ++e) if (s[e] > s[i1]) i1 = e;
      int i2 = (i1 == 0) ? 1 : 0;
      for (int e = 0; e < 8; ++e) if (e != i1 && s[e] > s[i2]) i2 = e;
      sel[tok] = i1 * 8 + i2;
    }
    __syncthreads();
  }
}

// ---------------------------------------------------------------------------
__global__ __launch_bounds__(256)
void build_lists(const int* __restrict__ sel, const float* __restrict__ probs,
                 int* __restrict__ counts, int* __restrict__ tokList,
                 float* __restrict__ gateList) {
  const int tok = blockIdx.x * 256 + threadIdx.x;
  const int sl = sel[tok];
  const int e1 = sl >> 3, e2 = sl & 7;
  const float p1 = probs[(size_t)tok * 8 + e1] * 0.5f;
  const float p2 = probs[(size_t)tok * 8 + e2] * 0.5f;
  int pos = atomicAdd(&counts[e1], 1);
  tokList[e1 * CAP + pos] = tok; gateList[e1 * CAP + pos] = p1;
  pos = atomicAdd(&counts[e2], 1);
  tokList[e2 * CAP + pos] = tok; gateList[e2 * CAP + pos] = p2;
}

__global__ void scan_counts(int* __restrict__ ctrl) {
  if (threadIdx.x == 0 && blockIdx.x == 0) {
    int rb = 0, s = 0;
    for (int e = 0; e < NEXP; ++e) {
      ctrl[9 + e]  = rb;
      ctrl[18 + e] = s;
      const int nrb = (ctrl[e] + 127) >> 7;
      rb += nrb; s += nrb * 128;
    }
    ctrl[17] = rb;
  }
}

// ---------------------------------------------------------------------------
extern "C" void kernel_launch(void* const* d_in, const int* in_sizes, int n_in,
                              void* d_out, int out_size, void* d_ws, size_t ws_size,
                              hipStream_t stream) {
  const float* x   = (const float*)d_in[0];
  const float* rW1 = (const float*)d_in[1];
  const float* rb1 = (const float*)d_in[2];
  const float* rW2 = (const float*)d_in[3];
  const float* rb2 = (const float*)d_in[4];
  const float* rW3 = (const float*)d_in[5];
  const float* rb3 = (const float*)d_in[6];
  const float* eW1 = (const float*)d_in[7];
  const float* eb1 = (const float*)d_in[8];
  const float* eW2 = (const float*)d_in[9];
  const float* eb2 = (const float*)d_in[10];
  const float* eW3 = (const float*)d_in[11];
  const float* eb3 = (const float*)d_in[12];

  float* outp  = (float*)d_out;                       // [16384][50]
  float* probs = outp + (size_t)NTOK * COUT;          // [16384][8]

  // ---- workspace carve with liveness unions (~248 MB) ----
  constexpr size_t SZ_X16  = (size_t)NTOK * DIM * 2;            // 33.55 MB
  constexpr size_t SZ_WT1  = (size_t)NEXP * H1 * DIM * 2;       // 33.55 MB
  constexpr size_t SZ_H2   = (size_t)PADROWS * H2 * 2;          // 69.5 MB
  constexpr size_t SZ_A    = (SZ_H2 > SZ_X16 + SZ_WT1) ? SZ_H2 : (SZ_X16 + SZ_WT1);
  constexpr size_t SZ_H1R16 = (size_t)NTOK * RH1 * 2;           // 16.78 MB
  constexpr size_t SZ_H2R32 = (size_t)NTOK * RH2 * 4;           // 16.78 MB
  constexpr size_t SZ_H1   = (size_t)PADROWS * H1 * 2;          // 139 MB
  constexpr size_t SZ_B    = (SZ_H1 > SZ_H1R16 + SZ_H2R32) ? SZ_H1 : (SZ_H1R16 + SZ_H2R32);

  char* p = (char*)d_ws;
  auto carve = [&](size_t bytes) {
    char* r = p;
    p += (bytes + 255) & ~(size_t)255;
    return r;
  };
  char* arenaA = carve(SZ_A);            // [x16 | Wt1]  U  h2
  char* arenaB = carve(SZ_B);            // [h1r16 | h2r32]  U  h1
  _Float16* Wt2  = (_Float16*)carve((size_t)NEXP * H2 * H1 * 2);  // 33.55 MB
  _Float16* Wt3  = (_Float16*)carve((size_t)NEXP * 64 * H2 * 2);  // 1 MB
  _Float16* rWt1 = (_Float16*)carve((size_t)RH1 * DIM * 2);       // 1 MB
  _Float16* rWt2 = (_Float16*)carve((size_t)RH2 * RH1 * 2);       // 0.26 MB
  int*   ctrl    = (int*)carve(256);
  int*   counts  = ctrl;
  int*   redoCnt = ctrl + 8;
  int*   sel     = (int*)carve((size_t)NTOK * 4);
  int*   redoList= (int*)carve((size_t)NTOK * 4);
  int*   tokList = (int*)carve((size_t)NEXP * CAP * 4);
  float* gateList= (float*)carve((size_t)NEXP * CAP * 4);

  _Float16* x16   = (_Float16*)arenaA;               // live: conv .. expert L1
  _Float16* Wt1   = (_Float16*)(arenaA + SZ_X16);    // live: conv .. expert L1
  _Float16* h2    = (_Float16*)arenaA;               // live: expert L2 .. L3
  _Float16* h1r16 = (_Float16*)arenaB;               // live: router L1 .. L2
  float*    h2r   = (float*)(arenaB + SZ_H1R16);     // live: router L2 .. score
  _Float16* h1    = (_Float16*)arenaB;               // live: expert L1 .. L2

  // ---- zero init ----
  zero_ctrl<<<1, 64, 0, stream>>>(ctrl);
  zero_out<<<800, 256, 0, stream>>>(outp);

  // ---- conversions ----
  cvt_f32_f16<<<(NTOK * DIM) / (256 * 4), 256, 0, stream>>>(x, x16, NTOK * DIM);
  cvtT<<<dim3(H1 / 32, DIM / 32, NEXP), 256, 0, stream>>>(eW1, Wt1, DIM, H1, H1);
  cvtT<<<dim3(H2 / 32, H1 / 32, NEXP), 256, 0, stream>>>(eW2, Wt2, H1, H2, H2);
  cvtT<<<dim3(64 / 32, H2 / 32, NEXP), 256, 0, stream>>>(eW3, Wt3, H2, COUT, 64);
  cvtT<<<dim3(RH1 / 32, DIM / 32, 1), 256, 0, stream>>>(rW1, rWt1, DIM, RH1, RH1);
  cvtT<<<dim3(RH2 / 32, RH1 / 32, 1), 256, 0, stream>>>(rW2, rWt2, RH1, RH2, RH2);

  // ---- router (fp16 MFMA; fp64 redo covers ranking ambiguity) ----
  mfma_gemm<DIM, RH1, 0, true, false>
      <<<dim3(RH1 / 128, NTOK / 128), 256, 0, stream>>>(x16, rWt1, rb1, h1r16, nullptr, nullptr, NTOK);
  mfma_gemm<RH1, RH2, 0, true, true>
      <<<dim3(RH2 / 128, NTOK / 128), 256, 0, stream>>>(h1r16, rWt2, rb2, h2r, nullptr, nullptr, NTOK);
  router_score<<<NTOK / 256, 256, 0, stream>>>(h2r, rW3, rb3, probs, sel, redoList, redoCnt);
  router_redo<<<512, 256, 0, stream>>>(x, rW1, rb1, rW2, rb2, rW3, rb3, redoList, redoCnt, sel);
  build_lists<<<NTOK / 256, 256, 0, stream>>>(sel, probs, counts, tokList, gateList);
  scan_counts<<<1, 64, 0, stream>>>(ctrl);

  // ---- experts (fp16 MFMA, flattened padded row-block grids) ----
  mfma_gemm<DIM, H1, 1, true, false>
      <<<dim3(H1 / 128, MAXRB), 256, 0, stream>>>(x16, Wt1, eb1, h1, ctrl, tokList, 0);
  mfma_gemm<H1, H2, 2, true, false>
      <<<dim3(H2 / 128, MAXRB), 256, 0, stream>>>(h1, Wt2, eb2, h2, ctrl, tokList, 0);
  expert_out<<<dim3(1, MAXRB), 256, 0, stream>>>(h2, Wt3, eb3, outp, ctrl, tokList, gateList);

  (void)in_sizes; (void)n_in; (void)out_size; (void)ws_size;
}